// Round 2
// baseline (205.682 us; speedup 1.0000x reference)
//
#include <hip/hip_runtime.h>
#include <math.h>

// Problem constants (from reference): B=2, S=2048, D=1024, H=16, DH=64
#define BATCH 2
#define SEQ 2048
#define DMODEL 1024
#define NHEAD 16
#define DHEAD 64
#define QKV_COLS (3 * DMODEL)          // 3072
#define EPS 1e-8f
#define LOG2E 1.44269504f

typedef short bf16x8 __attribute__((ext_vector_type(8)));   // 8 bf16 (4 VGPRs)
typedef float f32x4 __attribute__((ext_vector_type(4)));    // 4 fp32 acc

// round-to-nearest-even float -> bf16 (as raw ushort)
static __device__ __forceinline__ unsigned short f2bf(float x) {
  unsigned u = __float_as_uint(x);
  u += 0x7fffu + ((u >> 16) & 1u);
  return (unsigned short)(u >> 16);
}

// pack two f32 -> (bf16(hi)<<16)|bf16(lo) in 3 VALU (round-half-up + v_perm)
static __device__ __forceinline__ unsigned pkbf(float lo, float hi) {
  const unsigned ul = __float_as_uint(lo) + 0x8000u;
  const unsigned uh = __float_as_uint(hi) + 0x8000u;
  return __builtin_amdgcn_perm(uh, ul, 0x07060302);  // [uh.hi16 | ul.hi16]
}

// async global->LDS, 16 B per lane (global_load_lds_dwordx4).
// LDS dest: wave-uniform base + lane*16 (m104/m108).
static __device__ __forceinline__ void async_ld16(const unsigned short* g,
                                                  unsigned short* l) {
  __builtin_amdgcn_global_load_lds(
      (const __attribute__((address_space(1))) void*)g,
      (__attribute__((address_space(3))) void*)(unsigned int)(unsigned long long)l,
      16, 0, 0);
}

// ---------------------------------------------------------------------------
// Prep 1: x f32 [M][K] -> bf16 same layout. 4 floats/thread.
// ---------------------------------------------------------------------------
__global__ __launch_bounds__(256) void convert_x_kernel(
    const float* __restrict__ x, unsigned short* __restrict__ xb) {
  const size_t i = ((size_t)blockIdx.x * 256 + threadIdx.x) * 4;
  const float4 a = *(const float4*)(x + i);
  ushort4 r;
  r.x = f2bf(a.x); r.y = f2bf(a.y); r.z = f2bf(a.z); r.w = f2bf(a.w);
  *(ushort4*)(xb + i) = r;
}

// ---------------------------------------------------------------------------
// Prep 2 (fused): both weight transposes in one launch.
// ---------------------------------------------------------------------------
__global__ __launch_bounds__(256) void transpose_w2_kernel(
    const float* __restrict__ W0, unsigned short* __restrict__ Wt0,
    const float* __restrict__ W1, unsigned short* __restrict__ Wt1) {
  __shared__ float tile[32][33];
  const int bx = blockIdx.x;
  const float* W;
  unsigned short* Wt;
  int N, n0;
  if (bx < 96) { W = W0; Wt = Wt0; N = QKV_COLS; n0 = bx * 32; }
  else         { W = W1; Wt = Wt1; N = DMODEL;   n0 = (bx - 96) * 32; }
  const int K = DMODEL;
  const int k0 = blockIdx.y * 32;
  const int tx = threadIdx.x, ty = threadIdx.y;
#pragma unroll
  for (int i = 0; i < 4; ++i)
    tile[ty + i * 8][tx] = W[(size_t)(k0 + ty + i * 8) * N + n0 + tx];
  __syncthreads();
#pragma unroll
  for (int i = 0; i < 4; ++i)
    Wt[(size_t)(n0 + ty + i * 8) * K + k0 + tx] = f2bf(tile[tx][ty + i * 8]);
}

// ---------------------------------------------------------------------------
// bf16 MFMA GEMM, double-buffered staging. C = A @ Bt^T. Used for GEMM2.
// ---------------------------------------------------------------------------
__global__ __launch_bounds__(256) void sgemm_bf16_kernel(
    const unsigned short* __restrict__ A, const unsigned short* __restrict__ Bt,
    float* __restrict__ C, int M, int N, int K) {
  __shared__ unsigned short As[2][128 * 32];   // [buf][m][k]
  __shared__ unsigned short Bs[2][128 * 32];   // [buf][n][k]

  const int t = threadIdx.x;
  const int w = t >> 6;
  const int lane = t & 63;
  const int quad = lane >> 4;
  const int lr = lane & 15;
  const int wr = w >> 1, wc = w & 1;
  const int m0 = blockIdx.y * 128;
  const int n0 = blockIdx.x * 128;

  const int srow = w * 32 + (lane >> 2);
  const int scol = (lane & 3) * 8;
  const unsigned short* ga = A + (size_t)(m0 + srow) * K + scol;
  const unsigned short* gb = Bt + (size_t)(n0 + srow) * K + scol;

  auto stage = [&](int k0, int bb) {
#pragma unroll
    for (int i = 0; i < 2; ++i) {
      async_ld16(ga + (size_t)(i * 16) * K + k0, &As[bb][(w * 32 + i * 16) * 32]);
      async_ld16(gb + (size_t)(i * 16) * K + k0, &Bs[bb][(w * 32 + i * 16) * 32]);
    }
  };

  f32x4 acc[4][4];
  const f32x4 zero4 = {0.f, 0.f, 0.f, 0.f};
#pragma unroll
  for (int i = 0; i < 4; ++i)
#pragma unroll
    for (int j = 0; j < 4; ++j) acc[i][j] = zero4;

  stage(0, 0);
  int bb = 0;
  for (int k0 = 0; k0 < K; k0 += 32, bb ^= 1) {
    __syncthreads();
    if (k0 + 32 < K) stage(k0 + 32, bb ^ 1);

    bf16x8 af[4], bfr[4];
#pragma unroll
    for (int i = 0; i < 4; ++i)
      af[i] = *(const bf16x8*)&As[bb][(wr * 64 + i * 16 + lr) * 32 + quad * 8];
#pragma unroll
    for (int j = 0; j < 4; ++j)
      bfr[j] = *(const bf16x8*)&Bs[bb][(wc * 64 + j * 16 + lr) * 32 + quad * 8];
#pragma unroll
    for (int i = 0; i < 4; ++i)
#pragma unroll
      for (int j = 0; j < 4; ++j)
        acc[i][j] = __builtin_amdgcn_mfma_f32_16x16x32_bf16(af[i], bfr[j], acc[i][j], 0, 0, 0);
  }

#pragma unroll
  for (int i = 0; i < 4; ++i)
#pragma unroll
    for (int r = 0; r < 4; ++r) {
      float* c = C + (size_t)(m0 + wr * 64 + i * 16 + quad * 4 + r) * N + n0 + wc * 64 + lr;
#pragma unroll
      for (int j = 0; j < 4; ++j) c[j * 16] = acc[i][j][r];
    }
}

// ---------------------------------------------------------------------------
// GEMM1 + fused qk-norm — R13: 256x256 8-phase schedule (m201 port).
// 512 threads = 8 waves (2M x 4N); per-wave output 128x64; BK=64; 128 KiB
// double-buffered LDS. Per K-tile: 4 phases, each = {12 ds_read_b128 for one
// C-quadrant, 2 global_load_lds prefetch, fused vmcnt(4)+s_barrier, 16 MFMA
// under setprio(1), s_barrier}. vmcnt NEVER drains to 0 in the main loop.
// Deadline proof: reads at phase P need data issued <= P-3 (covered by
// P-1's vmcnt(4)+barrier). Issue order per tile t+1: A-lo@p0, B-lo@p1,
// B-hi@p2, A-hi@p3; first reads at t+1.p0 (A-lo,B-lo), t+1.p1 (B-hi),
// t+1.p2 (A-hi) — all satisfied. Last tile drains 2 -> 0.
// LDS: [row][64] bf16 rows (128 B) with chunk-XOR swizzle c ^= row&7,
// applied as pre-swizzled GLOBAL source + linear load_lds dest + swizzled
// ds_read (rule #21): LDS[row][c] = global[row][c^(row&7)].
// ---------------------------------------------------------------------------
__global__ __launch_bounds__(512, 2) void qkv_gemm_norm_kernel(
    const unsigned short* __restrict__ A, const unsigned short* __restrict__ Bt,
    const float* __restrict__ tau,
    unsigned short* __restrict__ Qh, unsigned short* __restrict__ Kh,
    unsigned short* __restrict__ Vh) {
  __shared__ unsigned short As[2][256 * 64];   // 64 KiB
  __shared__ unsigned short Bs[2][256 * 64];   // 64 KiB

  const int K = DMODEL;
  const int t = threadIdx.x;
  const int w = t >> 6;            // 0..7
  const int lane = t & 63;
  const int quad = lane >> 4;
  const int lr = lane & 15;
  const int wr = w >> 2;           // 0..1 (M)
  const int wc = w & 3;            // 0..3 (N)
  const int m0 = blockIdx.y * 256;
  const int n0 = blockIdx.x * 256;
  const int swz = lr & 7;          // read-side XOR key (= row&7 of frag rows)

  // staging: per instr a wave fills 8 rows x 128 B; lane l -> row l>>3,
  // chunk l&7; source chunk pre-swizzled (l&7)^(l>>3) (base rows %8==0).
  const int rrow = lane >> 3;                  // 0..7
  const int swc = ((lane & 7) ^ rrow) * 8;     // swizzled source chunk (shorts)

  // A regions: lo = tile rows {0-63,128-191} (read phases 0,1);
  //            hi = {64-127,192-255} (read phases 2,3).
  auto stA = [&](int k0, int bb, int hi) {
#pragma unroll
    for (int j = 0; j < 2; ++j) {
      const int L = w * 16 + j * 8;            // 0..127, %8==0
      const int row = hi * 64 + L + (L & 64);
      async_ld16(A + (size_t)(m0 + row + rrow) * K + k0 + swc, &As[bb][row * 64]);
    }
  };
  // B regions: lo = rows with (row&63)<32 (read phases 0,2);
  //            hi = (row&63)>=32 (read phases 1,3).
  auto stB = [&](int k0, int bb, int hi) {
#pragma unroll
    for (int j = 0; j < 2; ++j) {
      const int L = w * 16 + j * 8;
      const int row = ((L & ~31) << 1) + (L & 31) + hi * 32;
      async_ld16(Bt + (size_t)(n0 + row + rrow) * K + k0 + swc, &Bs[bb][row * 64]);
    }
  };

  f32x4 acc[8][4];
  const f32x4 zero4 = {0.f, 0.f, 0.f, 0.f};
#pragma unroll
  for (int i = 0; i < 8; ++i)
#pragma unroll
    for (int j = 0; j < 4; ++j) acc[i][j] = zero4;

  // one phase: quadrant (mB,nB) over full BK=64; stage + fused wait+barrier.
#define PHASE(bb_, mB_, nB_, STAGEBODY, WAITBODY)                              \
  {                                                                            \
    bf16x8 af[4][2], bq[2][2];                                                 \
    _Pragma("unroll")                                                          \
    for (int m2 = 0; m2 < 4; ++m2)                                             \
      _Pragma("unroll")                                                        \
      for (int kk = 0; kk < 2; ++kk)                                           \
        af[m2][kk] = *(const bf16x8*)&As[bb_][                                 \
            (wr * 128 + ((mB_) * 4 + m2) * 16 + lr) * 64 +                     \
            (((kk * 4 + quad) ^ swz) * 8)];                                    \
    _Pragma("unroll")                                                          \
    for (int n2 = 0; n2 < 2; ++n2)                                             \
      _Pragma("unroll")                                                        \
      for (int kk = 0; kk < 2; ++kk)                                           \
        bq[n2][kk] = *(const bf16x8*)&Bs[bb_][                                 \
            (wc * 64 + ((nB_) * 2 + n2) * 16 + lr) * 64 +                      \
            (((kk * 4 + quad) ^ swz) * 8)];                                    \
    STAGEBODY;                                                                 \
    WAITBODY;                                                                  \
    __builtin_amdgcn_s_setprio(1);                                             \
    _Pragma("unroll")                                                          \
    for (int m2 = 0; m2 < 4; ++m2)                                             \
      _Pragma("unroll")                                                        \
      for (int n2 = 0; n2 < 2; ++n2)                                           \
        _Pragma("unroll")                                                      \
        for (int kk = 0; kk < 2; ++kk)                                         \
          acc[(mB_) * 4 + m2][(nB_) * 2 + n2] =                                \
              __builtin_amdgcn_mfma_f32_16x16x32_bf16(                         \
                  af[m2][kk], bq[n2][kk], acc[(mB_) * 4 + m2][(nB_) * 2 + n2], \
                  0, 0, 0);                                                    \
    __builtin_amdgcn_s_setprio(0);                                             \
    __builtin_amdgcn_s_barrier();                                              \
  }

#define WAIT4 asm volatile("s_waitcnt vmcnt(4)\ns_barrier" ::: "memory")
#define WAIT2 asm volatile("s_waitcnt vmcnt(2)\ns_barrier" ::: "memory")
#define WAIT0 asm volatile("s_waitcnt vmcnt(0)\ns_barrier" ::: "memory")
#define WAITB asm volatile("s_barrier" ::: "memory")
#define NOSTAGE ((void)0)

  // prologue: tile 0 -> buf 0, in consume order; keep newest 4 in flight.
  stA(0, 0, 0); stB(0, 0, 0); stB(0, 0, 1); stA(0, 0, 1);
  WAIT4;   // A-lo,B-lo(0) done; B-hi,A-hi(0) in flight

  const int NT = K / 64;   // 16
  for (int tt = 0; tt < NT - 1; ++tt) {
    const int bb = tt & 1, nb = bb ^ 1;
    const int k0n = (tt + 1) * 64;
    PHASE(bb, 0, 0, stA(k0n, nb, 0), WAIT4);
    PHASE(bb, 0, 1, stB(k0n, nb, 0), WAIT4);
    PHASE(bb, 1, 0, stB(k0n, nb, 1), WAIT4);
    PHASE(bb, 1, 1, stA(k0n, nb, 1), WAIT4);
  }
  {  // last tile: drain 2 -> 0
    const int bb = (NT - 1) & 1;
    PHASE(bb, 0, 0, NOSTAGE, WAIT2);
    PHASE(bb, 0, 1, NOSTAGE, WAIT0);
    PHASE(bb, 1, 0, NOSTAGE, WAITB);
    PHASE(bb, 1, 1, NOSTAGE, WAITB);
  }
#undef PHASE

  // Epilogue: wave-uniform (which, head); wave's 64-col span = one head.
  const int col0 = n0 + wc * 64;
  const int which = col0 >> 10;             // 0=q, 1=k, 2=v
  const int h = (col0 & 1023) >> 6;
  const float tsc = tau[h] * 0.125f * LOG2E;
  unsigned short* dst = (which == 0) ? Qh : (which == 1) ? Kh : Vh;

#pragma unroll
  for (int m = 0; m < 8; ++m)
#pragma unroll
    for (int r = 0; r < 4; ++r) {
      const int s = m0 + wr * 128 + m * 16 + quad * 4 + r;   // row 0..4095
      unsigned short* ar =
          dst + (((size_t)((s >> 11) * NHEAD + h)) * SEQ + (s & 2047)) * DHEAD;
      float scale;
      if (which == 2) {
        scale = 1.0f;
      } else {
        float ss = 0.f;
#pragma unroll
        for (int n = 0; n < 4; ++n) ss += acc[m][n][r] * acc[m][n][r];
        ss += __shfl_xor(ss, 1, 16);
        ss += __shfl_xor(ss, 2, 16);
        ss += __shfl_xor(ss, 4, 16);
        ss += __shfl_xor(ss, 8, 16);
        scale = 1.0f / (sqrtf(ss) + EPS);
        if (which == 0) scale *= tsc;       // tau/sqrt(DH) * log2e into Q
      }
#pragma unroll
      for (int n = 0; n < 4; ++n) ar[n * 16 + lr] = f2bf(acc[m][n][r] * scale);
    }
}

// ---------------------------------------------------------------------------
// V transpose: Vh [BH][S][DH] -> Vt [BH][DH][S]. 64x64 LDS tiles.
// ---------------------------------------------------------------------------
__global__ __launch_bounds__(256) void vtrans_kernel(
    const unsigned short* __restrict__ Vh, unsigned short* __restrict__ Vt) {
  __shared__ unsigned short tile[64][72];
  const int bh = blockIdx.x;
  const int s0 = blockIdx.y * 64;
  const int t = threadIdx.x;
  const int sr = t >> 2;          // 0..63
  const int dc = (t & 3) * 16;    // 0,16,32,48
  const unsigned short* src = Vh + ((size_t)bh * SEQ + s0 + sr) * DHEAD + dc;
  *(bf16x8*)&tile[sr][dc]     = *(const bf16x8*)(src);
  *(bf16x8*)&tile[sr][dc + 8] = *(const bf16x8*)(src + 8);
  __syncthreads();
  const int dr = t >> 2;          // 0..63 (d row)
  const int sc = (t & 3) * 16;    // s chunk
  unsigned short buf[16];
#pragma unroll
  for (int i = 0; i < 16; ++i) buf[i] = tile[sc + i][dr];
  unsigned short* dst = Vt + ((size_t)bh * DHEAD + dr) * SEQ + s0 + sc;
  *(bf16x8*)dst       = *(const bf16x8*)buf;
  *(bf16x8*)(dst + 8) = *(const bf16x8*)(buf + 8);
}

// ---------------------------------------------------------------------------
// Causal flash attention — R12 (unchanged this round).
// grid 1024: one q-64-block per 4-wave block; 32 KB LDS, 4 blocks/CU;
// balanced qb mapping; XOR-swizzled K/V tiles; P in registers via
// permlane32/16 swaps; setprio around MFMA clusters.
// ---------------------------------------------------------------------------
__global__ __launch_bounds__(256, 4) void attn_kernel(
    const unsigned short* __restrict__ Qh, const unsigned short* __restrict__ Kh,
    const unsigned short* __restrict__ Vt, unsigned short* __restrict__ attnb) {
  __shared__ unsigned short Ks[2][64 * 64];   // [buf][key][d']  swizzled chunks
  __shared__ unsigned short Vs[2][64 * 64];   // [buf][d][key']  swizzled chunks

  const int idx = blockIdx.x;
  const int bh = idx & 31;
  const int i2 = idx >> 5;                 // 0..31
  const int seg = i2 >> 3, G = i2 & 7;
  const int qb = (seg == 0) ? 31 - G : (seg == 1) ? G : (seg == 2) ? 23 - G : 8 + G;
  const int b = bh >> 4;
  const int h = bh & 15;
  const int t = threadIdx.x;
  const int w = t >> 6;
  const int lane = t & 63;
  const int quad = lane >> 4;
  const int lr = lane & 15;
  const int sw = lr & 7;                   // read-side XOR swizzle key (row&7)

  const unsigned short* Qp = Qh + (size_t)bh * SEQ * DHEAD;
  const unsigned short* Kp = Kh + (size_t)bh * SEQ * DHEAD;
  const unsigned short* Vp = Vt + (size_t)bh * DHEAD * SEQ;

  const int rrow = lane >> 3;                        // 0..7
  const int swc = ((lane & 7) ^ rrow) * 8;           // swizzled chunk, in shorts
  const int f0 = w * 4;

  auto stage = [&](int k0, int bb) {
#pragma unroll
    for (int ii = 0; ii < 4; ++ii) {
      const int fi = f0 + ii;
      if (fi < 8) {   // K tile rows = keys
        async_ld16(Kp + (size_t)(k0 + fi * 8 + rrow) * DHEAD + swc,
                   &Ks[bb][fi * 512]);
      } else {        // V^T tile rows = d
        const int g = fi - 8;
        async_ld16(Vp + (size_t)(g * 8 + rrow) * SEQ + k0 + swc,
                   &Vs[bb][g * 512]);
      }
    }
  };

  const f32x4 zero4 = {0.f, 0.f, 0.f, 0.f};
  f32x4 o[4];
  o[0] = o[1] = o[2] = o[3] = zero4;
  float l_ = 0.f;

  const int q0 = qb * 64 + w * 16;
  const unsigned short* qr = Qp + (size_t)(q0 + lr) * DHEAD;
  const bf16x8 aq0 = *(const bf16x8*)(qr + quad * 8);
  const bf16x8 aq1 = *(const bf16x8*)(qr + 32 + quad * 8);
  const int qrow = q0 + lr;        // this lane's q row (for diagonal mask)

  const int kend = qb * 64;        // last step's k0 (diagonal step)

  stage(0, 0);
  int bb = 0;

  for (int k0 = 0; k0 <= kend; k0 += 64, bb ^= 1) {
    __syncthreads();                       // buf bb staged; prev reads done
    if (k0 < kend) stage(k0 + 64, bb ^ 1);

    // --- QK^T (swapped: S^T = K * Q^T; lane holds 16 keys for q=lr) ---
    f32x4 c[4];
    __builtin_amdgcn_s_setprio(1);
#pragma unroll
    for (int kt = 0; kt < 4; ++kt) {
      const bf16x8 kf0 =
          *(const bf16x8*)&Ks[bb][(kt * 16 + lr) * 64 + ((quad ^ sw) * 8)];
      const bf16x8 kf1 =
          *(const bf16x8*)&Ks[bb][(kt * 16 + lr) * 64 + (((4 | quad) ^ sw) * 8)];
      f32x4 tt = __builtin_amdgcn_mfma_f32_16x16x32_bf16(kf0, aq0, zero4, 0, 0, 0);
      c[kt] = __builtin_amdgcn_mfma_f32_16x16x32_bf16(kf1, aq1, tt, 0, 0, 0);
    }
    __builtin_amdgcn_s_setprio(0);

    // --- fixed-max exp2 softmax, packed to bf16 pairs in registers ---
    unsigned plo[4], phi[4];
    float ps = 0.f;
    if (k0 == kend) {                      // diagonal step: causal mask
#pragma unroll
      for (int kt = 0; kt < 4; ++kt) {
        float p[4];
#pragma unroll
        for (int r = 0; r < 4; ++r) {
          const int key = k0 + kt * 16 + quad * 4 + r;
          p[r] = (key <= qrow) ? exp2f(c[kt][r]) : 0.f;
          ps += p[r];
        }
        plo[kt] = pkbf(p[0], p[1]);
        phi[kt] = pkbf(p[2], p[3]);
      }
    } else {
#pragma unroll
      for (int kt = 0; kt < 4; ++kt) {
        float p[4];
#pragma unroll
        for (int r = 0; r < 4; ++r) {
          p[r] = exp2f(c[kt][r]);
          ps += p[r];
        }
        plo[kt] = pkbf(p[0], p[1]);
        phi[kt] = pkbf(p[2], p[3]);
      }
    }
    l_ += ps;

    // --- permlane butterfly: compute layout -> PV A-operand layout ---
#pragma unroll
    for (int c2 = 0; c2 < 2; ++c2) {
      unsigned aLo = plo[2 * c2],     aHi = phi[2 * c2];
      unsigned bLo = plo[2 * c2 + 1], bHi = phi[2 * c2 + 1];
      asm("v_permlane32_swap_b32 %0, %1" : "+v"(aLo), "+v"(bLo));
      asm("v_permlane32_swap_b32 %0, %1" : "+v"(aHi), "+v"(bHi));
      asm("v_permlane16_swap_b32 %0, %1" : "+v"(aLo), "+v"(bLo));
      asm("v_permlane16_swap_b32 %0, %1" : "+v"(aHi), "+v"(bHi));
      union { unsigned u[4]; bf16x8 v; } pk;
      pk.u[0] = aLo; pk.u[1] = aHi; pk.u[2] = bLo; pk.u[3] = bHi;
      const bf16x8 pa = pk.v;
      __builtin_amdgcn_s_setprio(1);
#pragma unroll
      for (int nt = 0; nt < 4; ++nt) {
        const bf16x8 vb = *(const bf16x8*)&Vs[bb][(nt * 16 + lr) * 64 +
                                                  (((c2 * 4 + quad) ^ sw) * 8)];
        o[nt] = __builtin_amdgcn_mfma_f32_16x16x32_bf16(pa, vb, o[nt], 0, 0, 0);
      }
      __builtin_amdgcn_s_setprio(0);
    }
  }

  // epilogue
  float lt = l_;
  lt += __shfl_xor(lt, 16, 64);
  lt += __shfl_xor(lt, 32, 64);
  const float inv = 1.0f / lt;            // valid for q = lr
#pragma unroll
  for (int r = 0; r < 4; ++r) {
    const float invr = __shfl(inv, quad * 4 + r, 16);
    unsigned short* ar =
        attnb + ((size_t)(b * SEQ + q0 + quad * 4 + r)) * DMODEL + h * DHEAD;
#pragma unroll
    for (int nt = 0; nt < 4; ++nt) ar[nt * 16 + lr] = f2bf(o[nt][r] * invr);
  }
}

// ---------------------------------------------------------------------------
// Launch
// ---------------------------------------------------------------------------
extern "C" void kernel_launch(void* const* d_in, const int* in_sizes, int n_in,
                              void* d_out, int out_size, void* d_ws, size_t ws_size,
                              hipStream_t stream) {
  const float* x    = (const float*)d_in[0];
  // d_in[1]: fixed causal tril mask -> handled analytically, never read.
  const float* Wqkv = (const float*)d_in[2];
  const float* Wo   = (const float*)d_in[3];
  const float* tau  = (const float*)d_in[4];
  float* out = (float*)d_out;

  // workspace layout (~50 MB)
  unsigned short* attnb = (unsigned short*)d_ws;                      // bf16 [B,S,D]
  unsigned short* Qh = attnb + (size_t)BATCH * SEQ * DMODEL;          // bf16 [B,H,S,DH]
  unsigned short* Kh = Qh + (size_t)BATCH * NHEAD * SEQ * DHEAD;
  unsigned short* Vh = Kh + (size_t)BATCH * NHEAD * SEQ * DHEAD;
  unsigned short* Xb = Vh + (size_t)BATCH * NHEAD * SEQ * DHEAD;      // bf16 [B*S][D]
  unsigned short* Wqkv_t = Xb + (size_t)BATCH * SEQ * DMODEL;         // bf16 [3D][D]
  unsigned short* Wo_t = Wqkv_t + (size_t)DMODEL * QKV_COLS;          // bf16 [D][D]
  unsigned short* Vt = Wo_t + (size_t)DMODEL * DMODEL;                // bf16 [BH][DH][S]

  const int M = BATCH * SEQ;  // 4096

  // 0) prep: bf16 conversion + fused weight transposes
  convert_x_kernel<<<(M * DMODEL) / (256 * 4), 256, 0, stream>>>(x, Xb);
  transpose_w2_kernel<<<dim3(128, 32), dim3(32, 8), 0, stream>>>(
      Wqkv, Wqkv_t, Wo, Wo_t);

  // 1) GEMM1 + fused qk-norm (256x256 8-phase) -> Qh/Kh/Vh bf16 head-major
  qkv_gemm_norm_kernel<<<dim3(QKV_COLS / 256, M / 256), 512, 0, stream>>>(
      Xb, Wqkv_t, tau, Qh, Kh, Vh);

  // 2) V -> V^T [BH][DH][S]
  vtrans_kernel<<<dim3(BATCH * NHEAD, SEQ / 64), 256, 0, stream>>>(Vh, Vt);

  // 3) causal MFMA flash attention -> attnb bf16 [B,S,D]
  attn_kernel<<<dim3(1024), 256, 0, stream>>>(Qh, Kh, Vt, attnb);

  // 4) out = attn @ Wo  (M=4096, N=1024, K=1024), f32 out
  sgemm_bf16_kernel<<<dim3(DMODEL / 128, M / 128), 256, 0, stream>>>(
      attnb, Wo_t, out, M, DMODEL, DMODEL);
}

// Round 3
// 203.113 us; speedup vs baseline: 1.0127x; 1.0127x over previous
//
#include <hip/hip_runtime.h>
#include <math.h>

// Problem constants (from reference): B=2, S=2048, D=1024, H=16, DH=64
#define BATCH 2
#define SEQ 2048
#define DMODEL 1024
#define NHEAD 16
#define DHEAD 64
#define QKV_COLS (3 * DMODEL)          // 3072
#define EPS 1e-8f
#define LOG2E 1.44269504f

typedef short bf16x8 __attribute__((ext_vector_type(8)));   // 8 bf16 (4 VGPRs)
typedef float f32x4 __attribute__((ext_vector_type(4)));    // 4 fp32 acc

// round-to-nearest-even float -> bf16 (as raw ushort)
static __device__ __forceinline__ unsigned short f2bf(float x) {
  unsigned u = __float_as_uint(x);
  u += 0x7fffu + ((u >> 16) & 1u);
  return (unsigned short)(u >> 16);
}

// pack two f32 -> (bf16(hi)<<16)|bf16(lo) in 3 VALU (round-half-up + v_perm)
static __device__ __forceinline__ unsigned pkbf(float lo, float hi) {
  const unsigned ul = __float_as_uint(lo) + 0x8000u;
  const unsigned uh = __float_as_uint(hi) + 0x8000u;
  return __builtin_amdgcn_perm(uh, ul, 0x07060302);  // [uh.hi16 | ul.hi16]
}

// async global->LDS, 16 B per lane (global_load_lds_dwordx4).
// LDS dest: wave-uniform base + lane*16 (m104/m108).
static __device__ __forceinline__ void async_ld16(const unsigned short* g,
                                                  unsigned short* l) {
  __builtin_amdgcn_global_load_lds(
      (const __attribute__((address_space(1))) void*)g,
      (__attribute__((address_space(3))) void*)(unsigned int)(unsigned long long)l,
      16, 0, 0);
}

// ---------------------------------------------------------------------------
// Prep 1: x f32 [M][K] -> bf16 same layout. 4 floats/thread.
// ---------------------------------------------------------------------------
__global__ __launch_bounds__(256) void convert_x_kernel(
    const float* __restrict__ x, unsigned short* __restrict__ xb) {
  const size_t i = ((size_t)blockIdx.x * 256 + threadIdx.x) * 4;
  const float4 a = *(const float4*)(x + i);
  ushort4 r;
  r.x = f2bf(a.x); r.y = f2bf(a.y); r.z = f2bf(a.z); r.w = f2bf(a.w);
  *(ushort4*)(xb + i) = r;
}

// ---------------------------------------------------------------------------
// Prep 2 (fused): both weight transposes in one launch.
// ---------------------------------------------------------------------------
__global__ __launch_bounds__(256) void transpose_w2_kernel(
    const float* __restrict__ W0, unsigned short* __restrict__ Wt0,
    const float* __restrict__ W1, unsigned short* __restrict__ Wt1) {
  __shared__ float tile[32][33];
  const int bx = blockIdx.x;
  const float* W;
  unsigned short* Wt;
  int N, n0;
  if (bx < 96) { W = W0; Wt = Wt0; N = QKV_COLS; n0 = bx * 32; }
  else         { W = W1; Wt = Wt1; N = DMODEL;   n0 = (bx - 96) * 32; }
  const int K = DMODEL;
  const int k0 = blockIdx.y * 32;
  const int tx = threadIdx.x, ty = threadIdx.y;
#pragma unroll
  for (int i = 0; i < 4; ++i)
    tile[ty + i * 8][tx] = W[(size_t)(k0 + ty + i * 8) * N + n0 + tx];
  __syncthreads();
#pragma unroll
  for (int i = 0; i < 4; ++i)
    Wt[(size_t)(n0 + ty + i * 8) * K + k0 + tx] = f2bf(tile[tx][ty + i * 8]);
}

// ---------------------------------------------------------------------------
// bf16 MFMA GEMM, double-buffered staging. C = A @ Bt^T. Used for GEMM2.
// ---------------------------------------------------------------------------
__global__ __launch_bounds__(256) void sgemm_bf16_kernel(
    const unsigned short* __restrict__ A, const unsigned short* __restrict__ Bt,
    float* __restrict__ C, int M, int N, int K) {
  __shared__ unsigned short As[2][128 * 32];   // [buf][m][k]
  __shared__ unsigned short Bs[2][128 * 32];   // [buf][n][k]

  const int t = threadIdx.x;
  const int w = t >> 6;
  const int lane = t & 63;
  const int quad = lane >> 4;
  const int lr = lane & 15;
  const int wr = w >> 1, wc = w & 1;
  const int m0 = blockIdx.y * 128;
  const int n0 = blockIdx.x * 128;

  const int srow = w * 32 + (lane >> 2);
  const int scol = (lane & 3) * 8;
  const unsigned short* ga = A + (size_t)(m0 + srow) * K + scol;
  const unsigned short* gb = Bt + (size_t)(n0 + srow) * K + scol;

  auto stage = [&](int k0, int bb) {
#pragma unroll
    for (int i = 0; i < 2; ++i) {
      async_ld16(ga + (size_t)(i * 16) * K + k0, &As[bb][(w * 32 + i * 16) * 32]);
      async_ld16(gb + (size_t)(i * 16) * K + k0, &Bs[bb][(w * 32 + i * 16) * 32]);
    }
  };

  f32x4 acc[4][4];
  const f32x4 zero4 = {0.f, 0.f, 0.f, 0.f};
#pragma unroll
  for (int i = 0; i < 4; ++i)
#pragma unroll
    for (int j = 0; j < 4; ++j) acc[i][j] = zero4;

  stage(0, 0);
  int bb = 0;
  for (int k0 = 0; k0 < K; k0 += 32, bb ^= 1) {
    __syncthreads();
    if (k0 + 32 < K) stage(k0 + 32, bb ^ 1);

    bf16x8 af[4], bfr[4];
#pragma unroll
    for (int i = 0; i < 4; ++i)
      af[i] = *(const bf16x8*)&As[bb][(wr * 64 + i * 16 + lr) * 32 + quad * 8];
#pragma unroll
    for (int j = 0; j < 4; ++j)
      bfr[j] = *(const bf16x8*)&Bs[bb][(wc * 64 + j * 16 + lr) * 32 + quad * 8];
#pragma unroll
    for (int i = 0; i < 4; ++i)
#pragma unroll
      for (int j = 0; j < 4; ++j)
        acc[i][j] = __builtin_amdgcn_mfma_f32_16x16x32_bf16(af[i], bfr[j], acc[i][j], 0, 0, 0);
  }

#pragma unroll
  for (int i = 0; i < 4; ++i)
#pragma unroll
    for (int r = 0; r < 4; ++r) {
      float* c = C + (size_t)(m0 + wr * 64 + i * 16 + quad * 4 + r) * N + n0 + wc * 64 + lr;
#pragma unroll
      for (int j = 0; j < 4; ++j) c[j * 16] = acc[i][j][r];
    }
}

// ---------------------------------------------------------------------------
// GEMM1 + fused qk-norm — R14: 256x256 8-phase with MINIMAL LDS reads.
// R13 regression diagnosis: each phase loaded af[4][2]+bq[2][2] = 12
// ds_read_b128 per 16 MFMA (48/K-tile, 2x the minimum) -> LDS-pipe-bound
// (MfmaUtil 13%). R14 keeps R13's stage order {A-lo,B-lo,B-hi,A-hi} and
// vmcnt(4)-every-phase scheme (proven correct) but restructures phases for
// register reuse:
//   p0: LDA(m-lo)+LDB(n-lo) (12 reads)  MFMA m-lo x n-lo (16)
//   p1: LDB(n-hi)            (4 reads)  MFMA m-lo x n-hi (16, reuse af)
//   p2: LDA(m-hi)            (8 reads)  MFMA m-hi x n-lo (16, reuse bq-lo)
//   p3: (none)               (0 reads)  MFMA m-hi x n-hi (16, all reused)
// = 24 reads/K-tile (minimum). Deadlines (chunk -> first read): A-lo@tt-1.p0
// completes at tt-1.p2's vmcnt(4), read tt.p0 OK; B-lo@p1 -> p3 wait, read
// tt.p0 OK; B-hi@p2 -> tt.p0 wait, read tt.p1 OK; A-hi@p3 -> tt.p1 wait,
// read tt.p2 OK. Last tile drains 2 -> 0 (same as R13).
// LDS swizzle unchanged: LDS[row][c] = global[row][c^(row&7)], linear
// global_load_lds dest + pre-swizzled global source + swizzled ds_read.
// ---------------------------------------------------------------------------
__global__ __launch_bounds__(512, 2) void qkv_gemm_norm_kernel(
    const unsigned short* __restrict__ A, const unsigned short* __restrict__ Bt,
    const float* __restrict__ tau,
    unsigned short* __restrict__ Qh, unsigned short* __restrict__ Kh,
    unsigned short* __restrict__ Vh) {
  __shared__ unsigned short As[2][256 * 64];   // 64 KiB
  __shared__ unsigned short Bs[2][256 * 64];   // 64 KiB

  const int K = DMODEL;
  const int t = threadIdx.x;
  const int w = t >> 6;            // 0..7
  const int lane = t & 63;
  const int quad = lane >> 4;
  const int lr = lane & 15;
  const int wr = w >> 2;           // 0..1 (M)
  const int wc = w & 3;            // 0..3 (N)
  const int m0 = blockIdx.y * 256;
  const int n0 = blockIdx.x * 256;
  const int swz = lr & 7;          // read-side XOR key (= row&7 of frag rows)

  // staging: per instr a wave fills 8 rows x 128 B; lane l -> row l>>3,
  // chunk l&7; source chunk pre-swizzled (l&7)^(l>>3) (base rows %8==0).
  const int rrow = lane >> 3;                  // 0..7
  const int swc = ((lane & 7) ^ rrow) * 8;     // swizzled source chunk (shorts)

  // A regions: lo = tile rows {0-63,128-191} (read p0,p1);
  //            hi = {64-127,192-255} (read p2,p3).
  auto stA = [&](int k0, int bb, int hi) {
#pragma unroll
    for (int j = 0; j < 2; ++j) {
      const int L = w * 16 + j * 8;            // 0..127, %8==0
      const int row = hi * 64 + L + (L & 64);
      async_ld16(A + (size_t)(m0 + row + rrow) * K + k0 + swc, &As[bb][row * 64]);
    }
  };
  // B regions: lo = rows with (row&63)<32 (n-frags 0,1; read p0,p2);
  //            hi = (row&63)>=32 (n-frags 2,3; read p1,p3).
  auto stB = [&](int k0, int bb, int hi) {
#pragma unroll
    for (int j = 0; j < 2; ++j) {
      const int L = w * 16 + j * 8;
      const int row = ((L & ~31) << 1) + (L & 31) + hi * 32;
      async_ld16(Bt + (size_t)(n0 + row + rrow) * K + k0 + swc, &Bs[bb][row * 64]);
    }
  };

  f32x4 acc[8][4];
  const f32x4 zero4 = {0.f, 0.f, 0.f, 0.f};
#pragma unroll
  for (int i = 0; i < 8; ++i)
#pragma unroll
    for (int j = 0; j < 4; ++j) acc[i][j] = zero4;

  bf16x8 af[4][2];   // current m-half fragments [m2][kk]
  bf16x8 bq[4][2];   // all 4 n-frags           [n][kk]

#define LDA(bb_, mh_)                                                          \
  _Pragma("unroll")                                                            \
  for (int m2 = 0; m2 < 4; ++m2)                                               \
    _Pragma("unroll")                                                          \
    for (int kk = 0; kk < 2; ++kk)                                             \
      af[m2][kk] = *(const bf16x8*)&As[bb_][                                   \
          (wr * 128 + ((mh_) * 4 + m2) * 16 + lr) * 64 +                       \
          (((kk * 4 + quad) ^ swz) * 8)];

#define LDB(bb_, nh_)                                                          \
  _Pragma("unroll")                                                            \
  for (int n2 = 0; n2 < 2; ++n2)                                               \
    _Pragma("unroll")                                                          \
    for (int kk = 0; kk < 2; ++kk)                                             \
      bq[(nh_) * 2 + n2][kk] = *(const bf16x8*)&Bs[bb_][                       \
          (wc * 64 + ((nh_) * 2 + n2) * 16 + lr) * 64 +                        \
          (((kk * 4 + quad) ^ swz) * 8)];

#define MM(mh_, nh_)                                                           \
  __builtin_amdgcn_s_setprio(1);                                               \
  _Pragma("unroll")                                                            \
  for (int m2 = 0; m2 < 4; ++m2)                                               \
    _Pragma("unroll")                                                          \
    for (int n2 = 0; n2 < 2; ++n2)                                             \
      _Pragma("unroll")                                                        \
      for (int kk = 0; kk < 2; ++kk)                                           \
        acc[(mh_) * 4 + m2][(nh_) * 2 + n2] =                                  \
            __builtin_amdgcn_mfma_f32_16x16x32_bf16(                           \
                af[m2][kk], bq[(nh_) * 2 + n2][kk],                            \
                acc[(mh_) * 4 + m2][(nh_) * 2 + n2], 0, 0, 0);                 \
  __builtin_amdgcn_s_setprio(0);                                               \
  __builtin_amdgcn_s_barrier();

#define WAIT4 asm volatile("s_waitcnt vmcnt(4)\ns_barrier" ::: "memory")
#define WAIT2 asm volatile("s_waitcnt vmcnt(2)\ns_barrier" ::: "memory")
#define WAIT0 asm volatile("s_waitcnt vmcnt(0)\ns_barrier" ::: "memory")
#define WAITB asm volatile("s_barrier" ::: "memory")

  // prologue: tile 0 -> buf 0, in consume order; keep newest 4 in flight.
  stA(0, 0, 0); stB(0, 0, 0); stB(0, 0, 1); stA(0, 0, 1);
  WAIT4;   // A-lo,B-lo(0) done; B-hi,A-hi(0) in flight

  const int NT = K / 64;   // 16
  for (int tt = 0; tt < NT - 1; ++tt) {
    const int bb = tt & 1, nb = bb ^ 1;
    const int k0n = (tt + 1) * 64;
    LDA(bb, 0); LDB(bb, 0); stA(k0n, nb, 0); WAIT4; MM(0, 0);
    LDB(bb, 1);             stB(k0n, nb, 0); WAIT4; MM(0, 1);
    LDA(bb, 1);             stB(k0n, nb, 1); WAIT4; MM(1, 0);
                            stA(k0n, nb, 1); WAIT4; MM(1, 1);
  }
  {  // last tile: drain 2 -> 0
    const int bb = (NT - 1) & 1;
    LDA(bb, 0); LDB(bb, 0); WAIT2; MM(0, 0);
    LDB(bb, 1);             WAIT0; MM(0, 1);
    LDA(bb, 1);             WAITB; MM(1, 0);
                            WAITB; MM(1, 1);
  }
#undef LDA
#undef LDB
#undef MM

  // Epilogue: wave-uniform (which, head); wave's 64-col span = one head.
  const int col0 = n0 + wc * 64;
  const int which = col0 >> 10;             // 0=q, 1=k, 2=v
  const int h = (col0 & 1023) >> 6;
  const float tsc = tau[h] * 0.125f * LOG2E;
  unsigned short* dst = (which == 0) ? Qh : (which == 1) ? Kh : Vh;

#pragma unroll
  for (int m = 0; m < 8; ++m)
#pragma unroll
    for (int r = 0; r < 4; ++r) {
      const int s = m0 + wr * 128 + m * 16 + quad * 4 + r;   // row 0..4095
      unsigned short* ar =
          dst + (((size_t)((s >> 11) * NHEAD + h)) * SEQ + (s & 2047)) * DHEAD;
      float scale;
      if (which == 2) {
        scale = 1.0f;
      } else {
        float ss = 0.f;
#pragma unroll
        for (int n = 0; n < 4; ++n) ss += acc[m][n][r] * acc[m][n][r];
        ss += __shfl_xor(ss, 1, 16);
        ss += __shfl_xor(ss, 2, 16);
        ss += __shfl_xor(ss, 4, 16);
        ss += __shfl_xor(ss, 8, 16);
        scale = 1.0f / (sqrtf(ss) + EPS);
        if (which == 0) scale *= tsc;       // tau/sqrt(DH) * log2e into Q
      }
#pragma unroll
      for (int n = 0; n < 4; ++n) ar[n * 16 + lr] = f2bf(acc[m][n][r] * scale);
    }
}

// ---------------------------------------------------------------------------
// V transpose: Vh [BH][S][DH] -> Vt [BH][DH][S]. 64x64 LDS tiles.
// ---------------------------------------------------------------------------
__global__ __launch_bounds__(256) void vtrans_kernel(
    const unsigned short* __restrict__ Vh, unsigned short* __restrict__ Vt) {
  __shared__ unsigned short tile[64][72];
  const int bh = blockIdx.x;
  const int s0 = blockIdx.y * 64;
  const int t = threadIdx.x;
  const int sr = t >> 2;          // 0..63
  const int dc = (t & 3) * 16;    // 0,16,32,48
  const unsigned short* src = Vh + ((size_t)bh * SEQ + s0 + sr) * DHEAD + dc;
  *(bf16x8*)&tile[sr][dc]     = *(const bf16x8*)(src);
  *(bf16x8*)&tile[sr][dc + 8] = *(const bf16x8*)(src + 8);
  __syncthreads();
  const int dr = t >> 2;          // 0..63 (d row)
  const int sc = (t & 3) * 16;    // s chunk
  unsigned short buf[16];
#pragma unroll
  for (int i = 0; i < 16; ++i) buf[i] = tile[sc + i][dr];
  unsigned short* dst = Vt + ((size_t)bh * DHEAD + dr) * SEQ + s0 + sc;
  *(bf16x8*)dst       = *(const bf16x8*)buf;
  *(bf16x8*)(dst + 8) = *(const bf16x8*)(buf + 8);
}

// ---------------------------------------------------------------------------
// Causal flash attention — R12 (unchanged).
// grid 1024: one q-64-block per 4-wave block; 32 KB LDS, 4 blocks/CU;
// balanced qb mapping; XOR-swizzled K/V tiles; P in registers via
// permlane32/16 swaps; setprio around MFMA clusters.
// ---------------------------------------------------------------------------
__global__ __launch_bounds__(256, 4) void attn_kernel(
    const unsigned short* __restrict__ Qh, const unsigned short* __restrict__ Kh,
    const unsigned short* __restrict__ Vt, unsigned short* __restrict__ attnb) {
  __shared__ unsigned short Ks[2][64 * 64];   // [buf][key][d']  swizzled chunks
  __shared__ unsigned short Vs[2][64 * 64];   // [buf][d][key']  swizzled chunks

  const int idx = blockIdx.x;
  const int bh = idx & 31;
  const int i2 = idx >> 5;                 // 0..31
  const int seg = i2 >> 3, G = i2 & 7;
  const int qb = (seg == 0) ? 31 - G : (seg == 1) ? G : (seg == 2) ? 23 - G : 8 + G;
  const int b = bh >> 4;
  const int h = bh & 15;
  const int t = threadIdx.x;
  const int w = t >> 6;
  const int lane = t & 63;
  const int quad = lane >> 4;
  const int lr = lane & 15;
  const int sw = lr & 7;                   // read-side XOR swizzle key (row&7)

  const unsigned short* Qp = Qh + (size_t)bh * SEQ * DHEAD;
  const unsigned short* Kp = Kh + (size_t)bh * SEQ * DHEAD;
  const unsigned short* Vp = Vt + (size_t)bh * DHEAD * SEQ;

  const int rrow = lane >> 3;                        // 0..7
  const int swc = ((lane & 7) ^ rrow) * 8;           // swizzled chunk, in shorts
  const int f0 = w * 4;

  auto stage = [&](int k0, int bb) {
#pragma unroll
    for (int ii = 0; ii < 4; ++ii) {
      const int fi = f0 + ii;
      if (fi < 8) {   // K tile rows = keys
        async_ld16(Kp + (size_t)(k0 + fi * 8 + rrow) * DHEAD + swc,
                   &Ks[bb][fi * 512]);
      } else {        // V^T tile rows = d
        const int g = fi - 8;
        async_ld16(Vp + (size_t)(g * 8 + rrow) * SEQ + k0 + swc,
                   &Vs[bb][g * 512]);
      }
    }
  };

  const f32x4 zero4 = {0.f, 0.f, 0.f, 0.f};
  f32x4 o[4];
  o[0] = o[1] = o[2] = o[3] = zero4;
  float l_ = 0.f;

  const int q0 = qb * 64 + w * 16;
  const unsigned short* qr = Qp + (size_t)(q0 + lr) * DHEAD;
  const bf16x8 aq0 = *(const bf16x8*)(qr + quad * 8);
  const bf16x8 aq1 = *(const bf16x8*)(qr + 32 + quad * 8);
  const int qrow = q0 + lr;        // this lane's q row (for diagonal mask)

  const int kend = qb * 64;        // last step's k0 (diagonal step)

  stage(0, 0);
  int bb = 0;

  for (int k0 = 0; k0 <= kend; k0 += 64, bb ^= 1) {
    __syncthreads();                       // buf bb staged; prev reads done
    if (k0 < kend) stage(k0 + 64, bb ^ 1);

    // --- QK^T (swapped: S^T = K * Q^T; lane holds 16 keys for q=lr) ---
    f32x4 c[4];
    __builtin_amdgcn_s_setprio(1);
#pragma unroll
    for (int kt = 0; kt < 4; ++kt) {
      const bf16x8 kf0 =
          *(const bf16x8*)&Ks[bb][(kt * 16 + lr) * 64 + ((quad ^ sw) * 8)];
      const bf16x8 kf1 =
          *(const bf16x8*)&Ks[bb][(kt * 16 + lr) * 64 + (((4 | quad) ^ sw) * 8)];
      f32x4 tt = __builtin_amdgcn_mfma_f32_16x16x32_bf16(kf0, aq0, zero4, 0, 0, 0);
      c[kt] = __builtin_amdgcn_mfma_f32_16x16x32_bf16(kf1, aq1, tt, 0, 0, 0);
    }
    __builtin_amdgcn_s_setprio(0);

    // --- fixed-max exp2 softmax, packed to bf16 pairs in registers ---
    unsigned plo[4], phi[4];
    float ps = 0.f;
    if (k0 == kend) {                      // diagonal step: causal mask
#pragma unroll
      for (int kt = 0; kt < 4; ++kt) {
        float p[4];
#pragma unroll
        for (int r = 0; r < 4; ++r) {
          const int key = k0 + kt * 16 + quad * 4 + r;
          p[r] = (key <= qrow) ? exp2f(c[kt][r]) : 0.f;
          ps += p[r];
        }
        plo[kt] = pkbf(p[0], p[1]);
        phi[kt] = pkbf(p[2], p[3]);
      }
    } else {
#pragma unroll
      for (int kt = 0; kt < 4; ++kt) {
        float p[4];
#pragma unroll
        for (int r = 0; r < 4; ++r) {
          p[r] = exp2f(c[kt][r]);
          ps += p[r];
        }
        plo[kt] = pkbf(p[0], p[1]);
        phi[kt] = pkbf(p[2], p[3]);
      }
    }
    l_ += ps;

    // --- permlane butterfly: compute layout -> PV A-operand layout ---
#pragma unroll
    for (int c2 = 0; c2 < 2; ++c2) {
      unsigned aLo = plo[2 * c2],     aHi = phi[2 * c2];
      unsigned bLo = plo[2 * c2 + 1], bHi = phi[2 * c2 + 1];
      asm("v_permlane32_swap_b32 %0, %1" : "+v"(aLo), "+v"(bLo));
      asm("v_permlane32_swap_b32 %0, %1" : "+v"(aHi), "+v"(bHi));
      asm("v_permlane16_swap_b32 %0, %1" : "+v"(aLo), "+v"(bLo));
      asm("v_permlane16_swap_b32 %0, %1" : "+v"(aHi), "+v"(bHi));
      union { unsigned u[4]; bf16x8 v; } pk;
      pk.u[0] = aLo; pk.u[1] = aHi; pk.u[2] = bLo; pk.u[3] = bHi;
      const bf16x8 pa = pk.v;
      __builtin_amdgcn_s_setprio(1);
#pragma unroll
      for (int nt = 0; nt < 4; ++nt) {
        const bf16x8 vb = *(const bf16x8*)&Vs[bb][(nt * 16 + lr) * 64 +
                                                  (((c2 * 4 + quad) ^ sw) * 8)];
        o[nt] = __builtin_amdgcn_mfma_f32_16x16x32_bf16(pa, vb, o[nt], 0, 0, 0);
      }
      __builtin_amdgcn_s_setprio(0);
    }
  }

  // epilogue
  float lt = l_;
  lt += __shfl_xor(lt, 16, 64);
  lt += __shfl_xor(lt, 32, 64);
  const float inv = 1.0f / lt;            // valid for q = lr
#pragma unroll
  for (int r = 0; r < 4; ++r) {
    const float invr = __shfl(inv, quad * 4 + r, 16);
    unsigned short* ar =
        attnb + ((size_t)(b * SEQ + q0 + quad * 4 + r)) * DMODEL + h * DHEAD;
#pragma unroll
    for (int nt = 0; nt < 4; ++nt) ar[nt * 16 + lr] = f2bf(o[nt][r] * invr);
  }
}

// ---------------------------------------------------------------------------
// Launch
// ---------------------------------------------------------------------------
extern "C" void kernel_launch(void* const* d_in, const int* in_sizes, int n_in,
                              void* d_out, int out_size, void* d_ws, size_t ws_size,
                              hipStream_t stream) {
  const float* x    = (const float*)d_in[0];
  // d_in[1]: fixed causal tril mask -> handled analytically, never read.
  const float* Wqkv = (const float*)d_in[2];
  const float* Wo   = (const float*)d_in[3];
  const float* tau  = (const float*)d_in[4];
  float* out = (float*)d_out;

  // workspace layout (~50 MB)
  unsigned short* attnb = (unsigned short*)d_ws;                      // bf16 [B,S,D]
  unsigned short* Qh = attnb + (size_t)BATCH * SEQ * DMODEL;          // bf16 [B,H,S,DH]
  unsigned short* Kh = Qh + (size_t)BATCH * NHEAD * SEQ * DHEAD;
  unsigned short* Vh = Kh + (size_t)BATCH * NHEAD * SEQ * DHEAD;
  unsigned short* Xb = Vh + (size_t)BATCH * NHEAD * SEQ * DHEAD;      // bf16 [B*S][D]
  unsigned short* Wqkv_t = Xb + (size_t)BATCH * SEQ * DMODEL;         // bf16 [3D][D]
  unsigned short* Wo_t = Wqkv_t + (size_t)DMODEL * QKV_COLS;          // bf16 [D][D]
  unsigned short* Vt = Wo_t + (size_t)DMODEL * DMODEL;                // bf16 [BH][DH][S]

  const int M = BATCH * SEQ;  // 4096

  // 0) prep: bf16 conversion + fused weight transposes
  convert_x_kernel<<<(M * DMODEL) / (256 * 4), 256, 0, stream>>>(x, Xb);
  transpose_w2_kernel<<<dim3(128, 32), dim3(32, 8), 0, stream>>>(
      Wqkv, Wqkv_t, Wo, Wo_t);

  // 1) GEMM1 + fused qk-norm (256x256 8-phase, minimal reads) -> Qh/Kh/Vh
  qkv_gemm_norm_kernel<<<dim3(QKV_COLS / 256, M / 256), 512, 0, stream>>>(
      Xb, Wqkv_t, tau, Qh, Kh, Vh);

  // 2) V -> V^T [BH][DH][S]
  vtrans_kernel<<<dim3(BATCH * NHEAD, SEQ / 64), 256, 0, stream>>>(Vh, Vt);

  // 3) causal MFMA flash attention -> attnb bf16 [B,S,D]
  attn_kernel<<<dim3(1024), 256, 0, stream>>>(Qh, Kh, Vt, attnb);

  // 4) out = attn @ Wo  (M=4096, N=1024, K=1024), f32 out
  sgemm_bf16_kernel<<<dim3(DMODEL / 128, M / 128), 256, 0, stream>>>(
      attnb, Wo_t, out, M, DMODEL, DMODEL);
}

// Round 4
// 196.600 us; speedup vs baseline: 1.0462x; 1.0331x over previous
//
#include <hip/hip_runtime.h>
#include <math.h>

// Problem constants (from reference): B=2, S=2048, D=1024, H=16, DH=64
#define BATCH 2
#define SEQ 2048
#define DMODEL 1024
#define NHEAD 16
#define DHEAD 64
#define QKV_COLS (3 * DMODEL)          // 3072
#define EPS 1e-8f
#define LOG2E 1.44269504f

typedef short bf16x8 __attribute__((ext_vector_type(8)));   // 8 bf16 (4 VGPRs)
typedef float f32x4 __attribute__((ext_vector_type(4)));    // 4 fp32 acc

// round-to-nearest-even float -> bf16 (as raw ushort)
static __device__ __forceinline__ unsigned short f2bf(float x) {
  unsigned u = __float_as_uint(x);
  u += 0x7fffu + ((u >> 16) & 1u);
  return (unsigned short)(u >> 16);
}

// pack two f32 -> (bf16(hi)<<16)|bf16(lo) in 3 VALU (round-half-up + v_perm)
static __device__ __forceinline__ unsigned pkbf(float lo, float hi) {
  const unsigned ul = __float_as_uint(lo) + 0x8000u;
  const unsigned uh = __float_as_uint(hi) + 0x8000u;
  return __builtin_amdgcn_perm(uh, ul, 0x07060302);  // [uh.hi16 | ul.hi16]
}

// async global->LDS, 16 B per lane (global_load_lds_dwordx4).
// LDS dest: wave-uniform base + lane*16 (m104/m108).
static __device__ __forceinline__ void async_ld16(const unsigned short* g,
                                                  unsigned short* l) {
  __builtin_amdgcn_global_load_lds(
      (const __attribute__((address_space(1))) void*)g,
      (__attribute__((address_space(3))) void*)(unsigned int)(unsigned long long)l,
      16, 0, 0);
}

// ---------------------------------------------------------------------------
// Prep 1: x f32 [M][K] -> bf16 same layout. 4 floats/thread.
// ---------------------------------------------------------------------------
__global__ __launch_bounds__(256) void convert_x_kernel(
    const float* __restrict__ x, unsigned short* __restrict__ xb) {
  const size_t i = ((size_t)blockIdx.x * 256 + threadIdx.x) * 4;
  const float4 a = *(const float4*)(x + i);
  ushort4 r;
  r.x = f2bf(a.x); r.y = f2bf(a.y); r.z = f2bf(a.z); r.w = f2bf(a.w);
  *(ushort4*)(xb + i) = r;
}

// ---------------------------------------------------------------------------
// Prep 2 (fused): both weight transposes in one launch.
// ---------------------------------------------------------------------------
__global__ __launch_bounds__(256) void transpose_w2_kernel(
    const float* __restrict__ W0, unsigned short* __restrict__ Wt0,
    const float* __restrict__ W1, unsigned short* __restrict__ Wt1) {
  __shared__ float tile[32][33];
  const int bx = blockIdx.x;
  const float* W;
  unsigned short* Wt;
  int N, n0;
  if (bx < 96) { W = W0; Wt = Wt0; N = QKV_COLS; n0 = bx * 32; }
  else         { W = W1; Wt = Wt1; N = DMODEL;   n0 = (bx - 96) * 32; }
  const int K = DMODEL;
  const int k0 = blockIdx.y * 32;
  const int tx = threadIdx.x, ty = threadIdx.y;
#pragma unroll
  for (int i = 0; i < 4; ++i)
    tile[ty + i * 8][tx] = W[(size_t)(k0 + ty + i * 8) * N + n0 + tx];
  __syncthreads();
#pragma unroll
  for (int i = 0; i < 4; ++i)
    Wt[(size_t)(n0 + ty + i * 8) * K + k0 + tx] = f2bf(tile[tx][ty + i * 8]);
}

// ---------------------------------------------------------------------------
// GEMM2 — R15: 64x128 tiles, grid 8x64 = 512 blocks = 2/CU (was 128x128,
// 256 blocks = 1/CU -> single 4-wave barrier domain per CU, no stall
// overlap; same disease R10-attn had). 24 KiB LDS. XCD-chunked swizzle:
// each XCD gets 8 contiguous m-rows (A-panels exclusive, 1 MB/XCD).
// C = A @ Bt^T, f32 out. Assumes grid exactly dim3(8, 64), K=1024.
// ---------------------------------------------------------------------------
__global__ __launch_bounds__(256) void sgemm_bf16_kernel(
    const unsigned short* __restrict__ A, const unsigned short* __restrict__ Bt,
    float* __restrict__ C, int M, int N, int K) {
  __shared__ unsigned short As[2][64 * 32];    // [buf][m][k]   4 KiB each
  __shared__ unsigned short Bs[2][128 * 32];   // [buf][n][k]   8 KiB each

  const int t = threadIdx.x;
  const int w = t >> 6;
  const int lane = t & 63;
  const int quad = lane >> 4;
  const int lr = lane & 15;

  // T1 swizzle: dispatch-linear id -> XCD-chunked logical id (512 %% 8 == 0)
  const int orig = blockIdx.y * gridDim.x + blockIdx.x;   // gridDim.x == 8
  const int wg = (orig & 7) * 64 + (orig >> 3);
  const int bx = wg & 7, by = wg >> 3;                    // by: 0..63
  const int m0 = by * 64;
  const int n0 = bx * 128;

  const int srow = lane >> 2;        // 0..15
  const int scol = (lane & 3) * 8;   // 16B chunk within 32-short row

  // 12 async_ld16 per K-step: 4 A-quarters (16 rows) + 8 B-eighths.
  // Wave w issues fi = w*3 .. w*3+2.
  auto stage = [&](int k0, int bb) {
#pragma unroll
    for (int ii = 0; ii < 3; ++ii) {
      const int fi = w * 3 + ii;
      if (fi < 4) {
        async_ld16(A + (size_t)(m0 + fi * 16 + srow) * K + k0 + scol,
                   &As[bb][fi * 512]);
      } else {
        const int g = fi - 4;
        async_ld16(Bt + (size_t)(n0 + g * 16 + srow) * K + k0 + scol,
                   &Bs[bb][g * 512]);
      }
    }
  };

  f32x4 acc[4][2];
  const f32x4 zero4 = {0.f, 0.f, 0.f, 0.f};
#pragma unroll
  for (int i = 0; i < 4; ++i)
#pragma unroll
    for (int j = 0; j < 2; ++j) acc[i][j] = zero4;

  stage(0, 0);
  int bb = 0;
  for (int k0 = 0; k0 < K; k0 += 32, bb ^= 1) {
    __syncthreads();
    if (k0 + 32 < K) stage(k0 + 32, bb ^ 1);

    bf16x8 af[4], bfr[2];
#pragma unroll
    for (int i = 0; i < 4; ++i)
      af[i] = *(const bf16x8*)&As[bb][(i * 16 + lr) * 32 + quad * 8];
#pragma unroll
    for (int j = 0; j < 2; ++j)
      bfr[j] = *(const bf16x8*)&Bs[bb][(w * 32 + j * 16 + lr) * 32 + quad * 8];
#pragma unroll
    for (int i = 0; i < 4; ++i)
#pragma unroll
      for (int j = 0; j < 2; ++j)
        acc[i][j] = __builtin_amdgcn_mfma_f32_16x16x32_bf16(af[i], bfr[j], acc[i][j], 0, 0, 0);
  }

#pragma unroll
  for (int i = 0; i < 4; ++i)
#pragma unroll
    for (int r = 0; r < 4; ++r) {
      float* c = C + (size_t)(m0 + i * 16 + quad * 4 + r) * N + n0 + w * 32 + lr;
#pragma unroll
      for (int j = 0; j < 2; ++j) c[j * 16] = acc[i][j][r];
    }
}

// ---------------------------------------------------------------------------
// GEMM1 + fused qk-norm — R15: revert to the PROVEN R12 128x128 2-phase
// structure (53 us measured; the R13/R14 256x256 8-phase ports both landed
// at 68-73 us -> two falsified predictions, structure abandoned on this
// shape). One change vs R12: T1 XCD-chunked blockIdx swizzle so the 24
// blocks sharing an A-panel-row land on the same XCD (4 m-rows per XCD:
// A exclusive 1 MB/XCD; B re-reads served by L3). Predicts FETCH 36->~20GB.
// ---------------------------------------------------------------------------
__global__ __launch_bounds__(256) void qkv_gemm_norm_kernel(
    const unsigned short* __restrict__ A, const unsigned short* __restrict__ Bt,
    const float* __restrict__ tau,
    unsigned short* __restrict__ Qh, unsigned short* __restrict__ Kh,
    unsigned short* __restrict__ Vh) {
  __shared__ unsigned short As[2][128 * 32];
  __shared__ unsigned short Bs[2][128 * 32];

  const int K = DMODEL;
  const int t = threadIdx.x;
  const int w = t >> 6;
  const int lane = t & 63;
  const int quad = lane >> 4;
  const int lr = lane & 15;
  const int wr = w >> 1, wc = w & 1;

  // T1 swizzle: 768 blocks (24 x 32), 768 %% 8 == 0 -> bijective chunking;
  // XCD k gets 96 contiguous logical ids = 4 full m-rows of 24 col-blocks.
  const int orig = blockIdx.y * gridDim.x + blockIdx.x;   // gridDim.x == 24
  const int wg = (orig & 7) * 96 + (orig >> 3);
  const int bx = wg % 24, by = wg / 24;
  const int m0 = by * 128;
  const int n0 = bx * 128;

  const int srow = w * 32 + (lane >> 2);
  const int scol = (lane & 3) * 8;
  const unsigned short* ga = A + (size_t)(m0 + srow) * K + scol;
  const unsigned short* gb = Bt + (size_t)(n0 + srow) * K + scol;

  auto stage = [&](int k0, int bb) {
#pragma unroll
    for (int i = 0; i < 2; ++i) {
      async_ld16(ga + (size_t)(i * 16) * K + k0, &As[bb][(w * 32 + i * 16) * 32]);
      async_ld16(gb + (size_t)(i * 16) * K + k0, &Bs[bb][(w * 32 + i * 16) * 32]);
    }
  };

  f32x4 acc[4][4];
  const f32x4 zero4 = {0.f, 0.f, 0.f, 0.f};
#pragma unroll
  for (int i = 0; i < 4; ++i)
#pragma unroll
    for (int j = 0; j < 4; ++j) acc[i][j] = zero4;

  stage(0, 0);
  int bb = 0;
  for (int k0 = 0; k0 < K; k0 += 32, bb ^= 1) {
    __syncthreads();
    if (k0 + 32 < K) stage(k0 + 32, bb ^ 1);

    bf16x8 af[4], bfr[4];
#pragma unroll
    for (int i = 0; i < 4; ++i)
      af[i] = *(const bf16x8*)&As[bb][(wr * 64 + i * 16 + lr) * 32 + quad * 8];
#pragma unroll
    for (int j = 0; j < 4; ++j)
      bfr[j] = *(const bf16x8*)&Bs[bb][(wc * 64 + j * 16 + lr) * 32 + quad * 8];
#pragma unroll
    for (int i = 0; i < 4; ++i)
#pragma unroll
      for (int j = 0; j < 4; ++j)
        acc[i][j] = __builtin_amdgcn_mfma_f32_16x16x32_bf16(af[i], bfr[j], acc[i][j], 0, 0, 0);
  }

  // Epilogue: wave-uniform (which, head) from column block.
  const int col0 = n0 + wc * 64;
  const int which = col0 >> 10;             // 0=q, 1=k, 2=v
  const int h = (col0 & 1023) >> 6;
  const float tsc = tau[h] * 0.125f * LOG2E;
  unsigned short* dst = (which == 0) ? Qh : (which == 1) ? Kh : Vh;

#pragma unroll
  for (int i = 0; i < 4; ++i)
#pragma unroll
    for (int r = 0; r < 4; ++r) {
      const int s = m0 + wr * 64 + i * 16 + quad * 4 + r;   // global row 0..4095
      unsigned short* ar =
          dst + (((size_t)((s >> 11) * NHEAD + h)) * SEQ + (s & 2047)) * DHEAD;
      float scale;
      if (which == 2) {
        scale = 1.0f;
      } else {
        float ss = 0.f;
#pragma unroll
        for (int j = 0; j < 4; ++j) ss += acc[i][j][r] * acc[i][j][r];
        ss += __shfl_xor(ss, 1, 16);
        ss += __shfl_xor(ss, 2, 16);
        ss += __shfl_xor(ss, 4, 16);
        ss += __shfl_xor(ss, 8, 16);
        scale = 1.0f / (sqrtf(ss) + EPS);
        if (which == 0) scale *= tsc;       // tau/sqrt(DH) * log2e into Q
      }
#pragma unroll
      for (int j = 0; j < 4; ++j) ar[j * 16 + lr] = f2bf(acc[i][j][r] * scale);
    }
}

// ---------------------------------------------------------------------------
// V transpose: Vh [BH][S][DH] -> Vt [BH][DH][S]. 64x64 LDS tiles.
// ---------------------------------------------------------------------------
__global__ __launch_bounds__(256) void vtrans_kernel(
    const unsigned short* __restrict__ Vh, unsigned short* __restrict__ Vt) {
  __shared__ unsigned short tile[64][72];
  const int bh = blockIdx.x;
  const int s0 = blockIdx.y * 64;
  const int t = threadIdx.x;
  const int sr = t >> 2;          // 0..63
  const int dc = (t & 3) * 16;    // 0,16,32,48
  const unsigned short* src = Vh + ((size_t)bh * SEQ + s0 + sr) * DHEAD + dc;
  *(bf16x8*)&tile[sr][dc]     = *(const bf16x8*)(src);
  *(bf16x8*)&tile[sr][dc + 8] = *(const bf16x8*)(src + 8);
  __syncthreads();
  const int dr = t >> 2;          // 0..63 (d row)
  const int sc = (t & 3) * 16;    // s chunk
  unsigned short buf[16];
#pragma unroll
  for (int i = 0; i < 16; ++i) buf[i] = tile[sc + i][dr];
  unsigned short* dst = Vt + ((size_t)bh * DHEAD + dr) * SEQ + s0 + sc;
  *(bf16x8*)dst       = *(const bf16x8*)buf;
  *(bf16x8*)(dst + 8) = *(const bf16x8*)(buf + 8);
}

// ---------------------------------------------------------------------------
// Causal flash attention — R12 (unchanged).
// grid 1024: one q-64-block per 4-wave block; 32 KB LDS, 4 blocks/CU;
// balanced qb mapping; XOR-swizzled K/V tiles; P in registers via
// permlane32/16 swaps; setprio around MFMA clusters.
// ---------------------------------------------------------------------------
__global__ __launch_bounds__(256, 4) void attn_kernel(
    const unsigned short* __restrict__ Qh, const unsigned short* __restrict__ Kh,
    const unsigned short* __restrict__ Vt, unsigned short* __restrict__ attnb) {
  __shared__ unsigned short Ks[2][64 * 64];   // [buf][key][d']  swizzled chunks
  __shared__ unsigned short Vs[2][64 * 64];   // [buf][d][key']  swizzled chunks

  const int idx = blockIdx.x;
  const int bh = idx & 31;
  const int i2 = idx >> 5;                 // 0..31
  const int seg = i2 >> 3, G = i2 & 7;
  const int qb = (seg == 0) ? 31 - G : (seg == 1) ? G : (seg == 2) ? 23 - G : 8 + G;
  const int b = bh >> 4;
  const int h = bh & 15;
  const int t = threadIdx.x;
  const int w = t >> 6;
  const int lane = t & 63;
  const int quad = lane >> 4;
  const int lr = lane & 15;
  const int sw = lr & 7;                   // read-side XOR swizzle key (row&7)

  const unsigned short* Qp = Qh + (size_t)bh * SEQ * DHEAD;
  const unsigned short* Kp = Kh + (size_t)bh * SEQ * DHEAD;
  const unsigned short* Vp = Vt + (size_t)bh * DHEAD * SEQ;

  const int rrow = lane >> 3;                        // 0..7
  const int swc = ((lane & 7) ^ rrow) * 8;           // swizzled chunk, in shorts
  const int f0 = w * 4;

  auto stage = [&](int k0, int bb) {
#pragma unroll
    for (int ii = 0; ii < 4; ++ii) {
      const int fi = f0 + ii;
      if (fi < 8) {   // K tile rows = keys
        async_ld16(Kp + (size_t)(k0 + fi * 8 + rrow) * DHEAD + swc,
                   &Ks[bb][fi * 512]);
      } else {        // V^T tile rows = d
        const int g = fi - 8;
        async_ld16(Vp + (size_t)(g * 8 + rrow) * SEQ + k0 + swc,
                   &Vs[bb][g * 512]);
      }
    }
  };

  const f32x4 zero4 = {0.f, 0.f, 0.f, 0.f};
  f32x4 o[4];
  o[0] = o[1] = o[2] = o[3] = zero4;
  float l_ = 0.f;

  const int q0 = qb * 64 + w * 16;
  const unsigned short* qr = Qp + (size_t)(q0 + lr) * DHEAD;
  const bf16x8 aq0 = *(const bf16x8*)(qr + quad * 8);
  const bf16x8 aq1 = *(const bf16x8*)(qr + 32 + quad * 8);
  const int qrow = q0 + lr;        // this lane's q row (for diagonal mask)

  const int kend = qb * 64;        // last step's k0 (diagonal step)

  stage(0, 0);
  int bb = 0;

  for (int k0 = 0; k0 <= kend; k0 += 64, bb ^= 1) {
    __syncthreads();                       // buf bb staged; prev reads done
    if (k0 < kend) stage(k0 + 64, bb ^ 1);

    // --- QK^T (swapped: S^T = K * Q^T; lane holds 16 keys for q=lr) ---
    f32x4 c[4];
    __builtin_amdgcn_s_setprio(1);
#pragma unroll
    for (int kt = 0; kt < 4; ++kt) {
      const bf16x8 kf0 =
          *(const bf16x8*)&Ks[bb][(kt * 16 + lr) * 64 + ((quad ^ sw) * 8)];
      const bf16x8 kf1 =
          *(const bf16x8*)&Ks[bb][(kt * 16 + lr) * 64 + (((4 | quad) ^ sw) * 8)];
      f32x4 tt = __builtin_amdgcn_mfma_f32_16x16x32_bf16(kf0, aq0, zero4, 0, 0, 0);
      c[kt] = __builtin_amdgcn_mfma_f32_16x16x32_bf16(kf1, aq1, tt, 0, 0, 0);
    }
    __builtin_amdgcn_s_setprio(0);

    // --- fixed-max exp2 softmax, packed to bf16 pairs in registers ---
    unsigned plo[4], phi[4];
    float ps = 0.f;
    if (k0 == kend) {                      // diagonal step: causal mask
#pragma unroll
      for (int kt = 0; kt < 4; ++kt) {
        float p[4];
#pragma unroll
        for (int r = 0; r < 4; ++r) {
          const int key = k0 + kt * 16 + quad * 4 + r;
          p[r] = (key <= qrow) ? exp2f(c[kt][r]) : 0.f;
          ps += p[r];
        }
        plo[kt] = pkbf(p[0], p[1]);
        phi[kt] = pkbf(p[2], p[3]);
      }
    } else {
#pragma unroll
      for (int kt = 0; kt < 4; ++kt) {
        float p[4];
#pragma unroll
        for (int r = 0; r < 4; ++r) {
          p[r] = exp2f(c[kt][r]);
          ps += p[r];
        }
        plo[kt] = pkbf(p[0], p[1]);
        phi[kt] = pkbf(p[2], p[3]);
      }
    }
    l_ += ps;

    // --- permlane butterfly: compute layout -> PV A-operand layout ---
#pragma unroll
    for (int c2 = 0; c2 < 2; ++c2) {
      unsigned aLo = plo[2 * c2],     aHi = phi[2 * c2];
      unsigned bLo = plo[2 * c2 + 1], bHi = phi[2 * c2 + 1];
      asm("v_permlane32_swap_b32 %0, %1" : "+v"(aLo), "+v"(bLo));
      asm("v_permlane32_swap_b32 %0, %1" : "+v"(aHi), "+v"(bHi));
      asm("v_permlane16_swap_b32 %0, %1" : "+v"(aLo), "+v"(bLo));
      asm("v_permlane16_swap_b32 %0, %1" : "+v"(aHi), "+v"(bHi));
      union { unsigned u[4]; bf16x8 v; } pk;
      pk.u[0] = aLo; pk.u[1] = aHi; pk.u[2] = bLo; pk.u[3] = bHi;
      const bf16x8 pa = pk.v;
      __builtin_amdgcn_s_setprio(1);
#pragma unroll
      for (int nt = 0; nt < 4; ++nt) {
        const bf16x8 vb = *(const bf16x8*)&Vs[bb][(nt * 16 + lr) * 64 +
                                                  (((c2 * 4 + quad) ^ sw) * 8)];
        o[nt] = __builtin_amdgcn_mfma_f32_16x16x32_bf16(pa, vb, o[nt], 0, 0, 0);
      }
      __builtin_amdgcn_s_setprio(0);
    }
  }

  // epilogue
  float lt = l_;
  lt += __shfl_xor(lt, 16, 64);
  lt += __shfl_xor(lt, 32, 64);
  const float inv = 1.0f / lt;            // valid for q = lr
#pragma unroll
  for (int r = 0; r < 4; ++r) {
    const float invr = __shfl(inv, quad * 4 + r, 16);
    unsigned short* ar =
        attnb + ((size_t)(b * SEQ + q0 + quad * 4 + r)) * DMODEL + h * DHEAD;
#pragma unroll
    for (int nt = 0; nt < 4; ++nt) ar[nt * 16 + lr] = f2bf(o[nt][r] * invr);
  }
}

// ---------------------------------------------------------------------------
// Launch
// ---------------------------------------------------------------------------
extern "C" void kernel_launch(void* const* d_in, const int* in_sizes, int n_in,
                              void* d_out, int out_size, void* d_ws, size_t ws_size,
                              hipStream_t stream) {
  const float* x    = (const float*)d_in[0];
  // d_in[1]: fixed causal tril mask -> handled analytically, never read.
  const float* Wqkv = (const float*)d_in[2];
  const float* Wo   = (const float*)d_in[3];
  const float* tau  = (const float*)d_in[4];
  float* out = (float*)d_out;

  // workspace layout (~50 MB)
  unsigned short* attnb = (unsigned short*)d_ws;                      // bf16 [B,S,D]
  unsigned short* Qh = attnb + (size_t)BATCH * SEQ * DMODEL;          // bf16 [B,H,S,DH]
  unsigned short* Kh = Qh + (size_t)BATCH * NHEAD * SEQ * DHEAD;
  unsigned short* Vh = Kh + (size_t)BATCH * NHEAD * SEQ * DHEAD;
  unsigned short* Xb = Vh + (size_t)BATCH * NHEAD * SEQ * DHEAD;      // bf16 [B*S][D]
  unsigned short* Wqkv_t = Xb + (size_t)BATCH * SEQ * DMODEL;         // bf16 [3D][D]
  unsigned short* Wo_t = Wqkv_t + (size_t)DMODEL * QKV_COLS;          // bf16 [D][D]
  unsigned short* Vt = Wo_t + (size_t)DMODEL * DMODEL;                // bf16 [BH][DH][S]

  const int M = BATCH * SEQ;  // 4096

  // 0) prep: bf16 conversion + fused weight transposes
  convert_x_kernel<<<(M * DMODEL) / (256 * 4), 256, 0, stream>>>(x, Xb);
  transpose_w2_kernel<<<dim3(128, 32), dim3(32, 8), 0, stream>>>(
      Wqkv, Wqkv_t, Wo, Wo_t);

  // 1) GEMM1 + fused qk-norm (R12 2-phase 128^2 + XCD swizzle) -> Qh/Kh/Vh
  qkv_gemm_norm_kernel<<<dim3(QKV_COLS / 128, M / 128), 256, 0, stream>>>(
      Xb, Wqkv_t, tau, Qh, Kh, Vh);

  // 2) V -> V^T [BH][DH][S]
  vtrans_kernel<<<dim3(BATCH * NHEAD, SEQ / 64), 256, 0, stream>>>(Vh, Vt);

  // 3) causal MFMA flash attention -> attnb bf16 [B,S,D]
  attn_kernel<<<dim3(1024), 256, 0, stream>>>(Qh, Kh, Vt, attnb);

  // 4) out = attn @ Wo  (M=4096, N=1024, K=1024), f32 out
  //    64x128 tiles, 512 blocks = 2/CU, XCD-chunked swizzle
  sgemm_bf16_kernel<<<dim3(DMODEL / 128, M / 64), 256, 0, stream>>>(
      attnb, Wo_t, out, M, DMODEL, DMODEL);
}

// Round 5
// 194.380 us; speedup vs baseline: 1.0581x; 1.0114x over previous
//
#include <hip/hip_runtime.h>
#include <math.h>

// Problem constants (from reference): B=2, S=2048, D=1024, H=16, DH=64
#define BATCH 2
#define SEQ 2048
#define DMODEL 1024
#define NHEAD 16
#define DHEAD 64
#define QKV_COLS (3 * DMODEL)          // 3072
#define EPS 1e-8f
#define LOG2E 1.44269504f

typedef short bf16x8 __attribute__((ext_vector_type(8)));   // 8 bf16 (4 VGPRs)
typedef float f32x4 __attribute__((ext_vector_type(4)));    // 4 fp32 acc

// round-to-nearest-even float -> bf16 (as raw ushort)
static __device__ __forceinline__ unsigned short f2bf(float x) {
  unsigned u = __float_as_uint(x);
  u += 0x7fffu + ((u >> 16) & 1u);
  return (unsigned short)(u >> 16);
}

// pack two f32 -> one u32 of 2xbf16 in ONE VALU op (T12 recipe)
static __device__ __forceinline__ unsigned cvtpk(float lo, float hi) {
  unsigned r;
  asm("v_cvt_pk_bf16_f32 %0, %1, %2" : "=v"(r) : "v"(lo), "v"(hi));
  return r;
}

// async global->LDS, 16 B per lane (global_load_lds_dwordx4).
// LDS dest: wave-uniform base + lane*16 (m104/m108).
static __device__ __forceinline__ void async_ld16(const unsigned short* g,
                                                  unsigned short* l) {
  __builtin_amdgcn_global_load_lds(
      (const __attribute__((address_space(1))) void*)g,
      (__attribute__((address_space(3))) void*)(unsigned int)(unsigned long long)l,
      16, 0, 0);
}

// ---------------------------------------------------------------------------
// Prep 1: x f32 [M][K] -> bf16 same layout. 4 floats/thread.
// ---------------------------------------------------------------------------
__global__ __launch_bounds__(256) void convert_x_kernel(
    const float* __restrict__ x, unsigned short* __restrict__ xb) {
  const size_t i = ((size_t)blockIdx.x * 256 + threadIdx.x) * 4;
  const float4 a = *(const float4*)(x + i);
  ushort4 r;
  r.x = f2bf(a.x); r.y = f2bf(a.y); r.z = f2bf(a.z); r.w = f2bf(a.w);
  *(ushort4*)(xb + i) = r;
}

// ---------------------------------------------------------------------------
// Prep 2 (fused): both weight transposes in one launch.
// ---------------------------------------------------------------------------
__global__ __launch_bounds__(256) void transpose_w2_kernel(
    const float* __restrict__ W0, unsigned short* __restrict__ Wt0,
    const float* __restrict__ W1, unsigned short* __restrict__ Wt1) {
  __shared__ float tile[32][33];
  const int bx = blockIdx.x;
  const float* W;
  unsigned short* Wt;
  int N, n0;
  if (bx < 96) { W = W0; Wt = Wt0; N = QKV_COLS; n0 = bx * 32; }
  else         { W = W1; Wt = Wt1; N = DMODEL;   n0 = (bx - 96) * 32; }
  const int K = DMODEL;
  const int k0 = blockIdx.y * 32;
  const int tx = threadIdx.x, ty = threadIdx.y;
#pragma unroll
  for (int i = 0; i < 4; ++i)
    tile[ty + i * 8][tx] = W[(size_t)(k0 + ty + i * 8) * N + n0 + tx];
  __syncthreads();
#pragma unroll
  for (int i = 0; i < 4; ++i)
    Wt[(size_t)(n0 + ty + i * 8) * K + k0 + tx] = f2bf(tile[tx][ty + i * 8]);
}

// ---------------------------------------------------------------------------
// GEMM2 — R15: 64x128 tiles, grid 8x64 = 512 blocks = 2/CU. 24 KiB LDS.
// XCD-chunked swizzle. C = A @ Bt^T, f32 out. Grid exactly dim3(8, 64).
// ---------------------------------------------------------------------------
__global__ __launch_bounds__(256) void sgemm_bf16_kernel(
    const unsigned short* __restrict__ A, const unsigned short* __restrict__ Bt,
    float* __restrict__ C, int M, int N, int K) {
  __shared__ unsigned short As[2][64 * 32];    // [buf][m][k]   4 KiB each
  __shared__ unsigned short Bs[2][128 * 32];   // [buf][n][k]   8 KiB each

  const int t = threadIdx.x;
  const int w = t >> 6;
  const int lane = t & 63;
  const int quad = lane >> 4;
  const int lr = lane & 15;

  // T1 swizzle: dispatch-linear id -> XCD-chunked logical id (512 %% 8 == 0)
  const int orig = blockIdx.y * gridDim.x + blockIdx.x;   // gridDim.x == 8
  const int wg = (orig & 7) * 64 + (orig >> 3);
  const int bx = wg & 7, by = wg >> 3;                    // by: 0..63
  const int m0 = by * 64;
  const int n0 = bx * 128;

  const int srow = lane >> 2;        // 0..15
  const int scol = (lane & 3) * 8;   // 16B chunk within 32-short row

  // 12 async_ld16 per K-step: 4 A-quarters (16 rows) + 8 B-eighths.
  auto stage = [&](int k0, int bb) {
#pragma unroll
    for (int ii = 0; ii < 3; ++ii) {
      const int fi = w * 3 + ii;
      if (fi < 4) {
        async_ld16(A + (size_t)(m0 + fi * 16 + srow) * K + k0 + scol,
                   &As[bb][fi * 512]);
      } else {
        const int g = fi - 4;
        async_ld16(Bt + (size_t)(n0 + g * 16 + srow) * K + k0 + scol,
                   &Bs[bb][g * 512]);
      }
    }
  };

  f32x4 acc[4][2];
  const f32x4 zero4 = {0.f, 0.f, 0.f, 0.f};
#pragma unroll
  for (int i = 0; i < 4; ++i)
#pragma unroll
    for (int j = 0; j < 2; ++j) acc[i][j] = zero4;

  stage(0, 0);
  int bb = 0;
  for (int k0 = 0; k0 < K; k0 += 32, bb ^= 1) {
    __syncthreads();
    if (k0 + 32 < K) stage(k0 + 32, bb ^ 1);

    bf16x8 af[4], bfr[2];
#pragma unroll
    for (int i = 0; i < 4; ++i)
      af[i] = *(const bf16x8*)&As[bb][(i * 16 + lr) * 32 + quad * 8];
#pragma unroll
    for (int j = 0; j < 2; ++j)
      bfr[j] = *(const bf16x8*)&Bs[bb][(w * 32 + j * 16 + lr) * 32 + quad * 8];
#pragma unroll
    for (int i = 0; i < 4; ++i)
#pragma unroll
      for (int j = 0; j < 2; ++j)
        acc[i][j] = __builtin_amdgcn_mfma_f32_16x16x32_bf16(af[i], bfr[j], acc[i][j], 0, 0, 0);
  }

#pragma unroll
  for (int i = 0; i < 4; ++i)
#pragma unroll
    for (int r = 0; r < 4; ++r) {
      float* c = C + (size_t)(m0 + i * 16 + quad * 4 + r) * N + n0 + w * 32 + lr;
#pragma unroll
      for (int j = 0; j < 2; ++j) c[j * 16] = acc[i][j][r];
    }
}

// ---------------------------------------------------------------------------
// GEMM1 + fused qk-norm — R15 structure (proven): 128x128 2-phase + T1
// XCD-chunked swizzle (4 m-rows per XCD -> A-panels exclusive per L2).
// ---------------------------------------------------------------------------
__global__ __launch_bounds__(256) void qkv_gemm_norm_kernel(
    const unsigned short* __restrict__ A, const unsigned short* __restrict__ Bt,
    const float* __restrict__ tau,
    unsigned short* __restrict__ Qh, unsigned short* __restrict__ Kh,
    unsigned short* __restrict__ Vh) {
  __shared__ unsigned short As[2][128 * 32];
  __shared__ unsigned short Bs[2][128 * 32];

  const int K = DMODEL;
  const int t = threadIdx.x;
  const int w = t >> 6;
  const int lane = t & 63;
  const int quad = lane >> 4;
  const int lr = lane & 15;
  const int wr = w >> 1, wc = w & 1;

  // T1 swizzle: 768 blocks (24 x 32) -> XCD k gets 96 contiguous ids.
  const int orig = blockIdx.y * gridDim.x + blockIdx.x;   // gridDim.x == 24
  const int wg = (orig & 7) * 96 + (orig >> 3);
  const int bx = wg % 24, by = wg / 24;
  const int m0 = by * 128;
  const int n0 = bx * 128;

  const int srow = w * 32 + (lane >> 2);
  const int scol = (lane & 3) * 8;
  const unsigned short* ga = A + (size_t)(m0 + srow) * K + scol;
  const unsigned short* gb = Bt + (size_t)(n0 + srow) * K + scol;

  auto stage = [&](int k0, int bb) {
#pragma unroll
    for (int i = 0; i < 2; ++i) {
      async_ld16(ga + (size_t)(i * 16) * K + k0, &As[bb][(w * 32 + i * 16) * 32]);
      async_ld16(gb + (size_t)(i * 16) * K + k0, &Bs[bb][(w * 32 + i * 16) * 32]);
    }
  };

  f32x4 acc[4][4];
  const f32x4 zero4 = {0.f, 0.f, 0.f, 0.f};
#pragma unroll
  for (int i = 0; i < 4; ++i)
#pragma unroll
    for (int j = 0; j < 4; ++j) acc[i][j] = zero4;

  stage(0, 0);
  int bb = 0;
  for (int k0 = 0; k0 < K; k0 += 32, bb ^= 1) {
    __syncthreads();
    if (k0 + 32 < K) stage(k0 + 32, bb ^ 1);

    bf16x8 af[4], bfr[4];
#pragma unroll
    for (int i = 0; i < 4; ++i)
      af[i] = *(const bf16x8*)&As[bb][(wr * 64 + i * 16 + lr) * 32 + quad * 8];
#pragma unroll
    for (int j = 0; j < 4; ++j)
      bfr[j] = *(const bf16x8*)&Bs[bb][(wc * 64 + j * 16 + lr) * 32 + quad * 8];
#pragma unroll
    for (int i = 0; i < 4; ++i)
#pragma unroll
      for (int j = 0; j < 4; ++j)
        acc[i][j] = __builtin_amdgcn_mfma_f32_16x16x32_bf16(af[i], bfr[j], acc[i][j], 0, 0, 0);
  }

  // Epilogue: wave-uniform (which, head) from column block.
  const int col0 = n0 + wc * 64;
  const int which = col0 >> 10;             // 0=q, 1=k, 2=v
  const int h = (col0 & 1023) >> 6;
  const float tsc = tau[h] * 0.125f * LOG2E;
  unsigned short* dst = (which == 0) ? Qh : (which == 1) ? Kh : Vh;

#pragma unroll
  for (int i = 0; i < 4; ++i)
#pragma unroll
    for (int r = 0; r < 4; ++r) {
      const int s = m0 + wr * 64 + i * 16 + quad * 4 + r;   // global row 0..4095
      unsigned short* ar =
          dst + (((size_t)((s >> 11) * NHEAD + h)) * SEQ + (s & 2047)) * DHEAD;
      float scale;
      if (which == 2) {
        scale = 1.0f;
      } else {
        float ss = 0.f;
#pragma unroll
        for (int j = 0; j < 4; ++j) ss += acc[i][j][r] * acc[i][j][r];
        ss += __shfl_xor(ss, 1, 16);
        ss += __shfl_xor(ss, 2, 16);
        ss += __shfl_xor(ss, 4, 16);
        ss += __shfl_xor(ss, 8, 16);
        scale = 1.0f / (sqrtf(ss) + EPS);
        if (which == 0) scale *= tsc;       // tau/sqrt(DH) * log2e into Q
      }
#pragma unroll
      for (int j = 0; j < 4; ++j) ar[j * 16 + lr] = f2bf(acc[i][j][r] * scale);
    }
}

// ---------------------------------------------------------------------------
// V transpose: Vh [BH][S][DH] -> Vt [BH][DH][S]. 64x64 LDS tiles.
// ---------------------------------------------------------------------------
__global__ __launch_bounds__(256) void vtrans_kernel(
    const unsigned short* __restrict__ Vh, unsigned short* __restrict__ Vt) {
  __shared__ unsigned short tile[64][72];
  const int bh = blockIdx.x;
  const int s0 = blockIdx.y * 64;
  const int t = threadIdx.x;
  const int sr = t >> 2;          // 0..63
  const int dc = (t & 3) * 16;    // 0,16,32,48
  const unsigned short* src = Vh + ((size_t)bh * SEQ + s0 + sr) * DHEAD + dc;
  *(bf16x8*)&tile[sr][dc]     = *(const bf16x8*)(src);
  *(bf16x8*)&tile[sr][dc + 8] = *(const bf16x8*)(src + 8);
  __syncthreads();
  const int dr = t >> 2;          // 0..63 (d row)
  const int sc = (t & 3) * 16;    // s chunk
  unsigned short buf[16];
#pragma unroll
  for (int i = 0; i < 16; ++i) buf[i] = tile[sc + i][dr];
  unsigned short* dst = Vt + ((size_t)bh * DHEAD + dr) * SEQ + s0 + sc;
  *(bf16x8*)dst       = *(const bf16x8*)buf;
  *(bf16x8*)(dst + 8) = *(const bf16x8*)(buf + 8);
}

// ---------------------------------------------------------------------------
// Causal flash attention — R16: VALU diet.
// R15 counters: VALUBusy 60%, MfmaUtil 15%, conflicts 0 -> VALU-bound.
// Per-step VALU was ~190 cyc (16 exp2 + 16 ps-adds + 8 pkbf*3 + 8 permlane)
// vs 80 cyc MFMA. R16:
//  * pkbf (3 VALU/pair) -> v_cvt_pk_bf16_f32 (1 VALU/pair): -16 VALU/step.
//  * row-sum l via MFMA-with-ones: ol = mfma(pa, ones, ol) (2 MFMA/step)
//    replaces 16 scalar adds/step AND the epilogue shuffle-reduce; ol[r]
//    lands per-lane in C-layout row q=quad*4+r, matching the write. Also
//    makes numerator and denominator use identical bf16-rounded P.
// Rest unchanged: grid 1024 balanced qb mapping, 32 KB LDS 4 blocks/CU,
// XOR-swizzled K/V, P in registers via permlane32/16 swaps, setprio.
// ---------------------------------------------------------------------------
__global__ __launch_bounds__(256, 4) void attn_kernel(
    const unsigned short* __restrict__ Qh, const unsigned short* __restrict__ Kh,
    const unsigned short* __restrict__ Vt, unsigned short* __restrict__ attnb) {
  __shared__ unsigned short Ks[2][64 * 64];   // [buf][key][d']  swizzled chunks
  __shared__ unsigned short Vs[2][64 * 64];   // [buf][d][key']  swizzled chunks

  const int idx = blockIdx.x;
  const int bh = idx & 31;
  const int i2 = idx >> 5;                 // 0..31
  const int seg = i2 >> 3, G = i2 & 7;
  const int qb = (seg == 0) ? 31 - G : (seg == 1) ? G : (seg == 2) ? 23 - G : 8 + G;
  const int b = bh >> 4;
  const int h = bh & 15;
  const int t = threadIdx.x;
  const int w = t >> 6;
  const int lane = t & 63;
  const int quad = lane >> 4;
  const int lr = lane & 15;
  const int sw = lr & 7;                   // read-side XOR swizzle key (row&7)

  const unsigned short* Qp = Qh + (size_t)bh * SEQ * DHEAD;
  const unsigned short* Kp = Kh + (size_t)bh * SEQ * DHEAD;
  const unsigned short* Vp = Vt + (size_t)bh * DHEAD * SEQ;

  const int rrow = lane >> 3;                        // 0..7
  const int swc = ((lane & 7) ^ rrow) * 8;           // swizzled chunk, in shorts
  const int f0 = w * 4;

  auto stage = [&](int k0, int bb) {
#pragma unroll
    for (int ii = 0; ii < 4; ++ii) {
      const int fi = f0 + ii;
      if (fi < 8) {   // K tile rows = keys
        async_ld16(Kp + (size_t)(k0 + fi * 8 + rrow) * DHEAD + swc,
                   &Ks[bb][fi * 512]);
      } else {        // V^T tile rows = d
        const int g = fi - 8;
        async_ld16(Vp + (size_t)(g * 8 + rrow) * SEQ + k0 + swc,
                   &Vs[bb][g * 512]);
      }
    }
  };

  const f32x4 zero4 = {0.f, 0.f, 0.f, 0.f};
  f32x4 o[4];
  o[0] = o[1] = o[2] = o[3] = zero4;
  f32x4 ol = zero4;                 // row-sum accumulator (MFMA-with-ones)

  bf16x8 ones;
#pragma unroll
  for (int i = 0; i < 8; ++i) ones[i] = (short)0x3F80;   // bf16 1.0

  const int q0 = qb * 64 + w * 16;
  const unsigned short* qr = Qp + (size_t)(q0 + lr) * DHEAD;
  const bf16x8 aq0 = *(const bf16x8*)(qr + quad * 8);
  const bf16x8 aq1 = *(const bf16x8*)(qr + 32 + quad * 8);
  const int qrow = q0 + lr;        // this lane's q row (for diagonal mask)

  const int kend = qb * 64;        // last step's k0 (diagonal step)

  stage(0, 0);
  int bb = 0;

  for (int k0 = 0; k0 <= kend; k0 += 64, bb ^= 1) {
    __syncthreads();                       // buf bb staged; prev reads done
    if (k0 < kend) stage(k0 + 64, bb ^ 1);

    // --- QK^T (swapped: S^T = K * Q^T; lane holds 16 keys for q=lr) ---
    f32x4 c[4];
    __builtin_amdgcn_s_setprio(1);
#pragma unroll
    for (int kt = 0; kt < 4; ++kt) {
      const bf16x8 kf0 =
          *(const bf16x8*)&Ks[bb][(kt * 16 + lr) * 64 + ((quad ^ sw) * 8)];
      const bf16x8 kf1 =
          *(const bf16x8*)&Ks[bb][(kt * 16 + lr) * 64 + (((4 | quad) ^ sw) * 8)];
      f32x4 tt = __builtin_amdgcn_mfma_f32_16x16x32_bf16(kf0, aq0, zero4, 0, 0, 0);
      c[kt] = __builtin_amdgcn_mfma_f32_16x16x32_bf16(kf1, aq1, tt, 0, 0, 0);
    }
    __builtin_amdgcn_s_setprio(0);

    // --- fixed-max exp2 softmax, packed to bf16 via v_cvt_pk (1 VALU/pair)
    unsigned plo[4], phi[4];
    if (k0 == kend) {                      // diagonal step: causal mask
#pragma unroll
      for (int kt = 0; kt < 4; ++kt) {
        float p[4];
#pragma unroll
        for (int r = 0; r < 4; ++r) {
          const int key = k0 + kt * 16 + quad * 4 + r;
          p[r] = (key <= qrow) ? exp2f(c[kt][r]) : 0.f;
        }
        plo[kt] = cvtpk(p[0], p[1]);
        phi[kt] = cvtpk(p[2], p[3]);
      }
    } else {
#pragma unroll
      for (int kt = 0; kt < 4; ++kt) {
        plo[kt] = cvtpk(exp2f(c[kt][0]), exp2f(c[kt][1]));
        phi[kt] = cvtpk(exp2f(c[kt][2]), exp2f(c[kt][3]));
      }
    }

    // --- permlane butterfly: compute layout -> PV A-operand layout ---
#pragma unroll
    for (int c2 = 0; c2 < 2; ++c2) {
      unsigned aLo = plo[2 * c2],     aHi = phi[2 * c2];
      unsigned bLo = plo[2 * c2 + 1], bHi = phi[2 * c2 + 1];
      asm("v_permlane32_swap_b32 %0, %1" : "+v"(aLo), "+v"(bLo));
      asm("v_permlane32_swap_b32 %0, %1" : "+v"(aHi), "+v"(bHi));
      asm("v_permlane16_swap_b32 %0, %1" : "+v"(aLo), "+v"(bLo));
      asm("v_permlane16_swap_b32 %0, %1" : "+v"(aHi), "+v"(bHi));
      union { unsigned u[4]; bf16x8 v; } pk;
      pk.u[0] = aLo; pk.u[1] = aHi; pk.u[2] = bLo; pk.u[3] = bHi;
      const bf16x8 pa = pk.v;
      __builtin_amdgcn_s_setprio(1);
#pragma unroll
      for (int nt = 0; nt < 4; ++nt) {
        const bf16x8 vb = *(const bf16x8*)&Vs[bb][(nt * 16 + lr) * 64 +
                                                  (((c2 * 4 + quad) ^ sw) * 8)];
        o[nt] = __builtin_amdgcn_mfma_f32_16x16x32_bf16(pa, vb, o[nt], 0, 0, 0);
      }
      // row-sum: all 16 output cols identical = sum_k P[q][k]; accumulates
      // across steps. ol[r] = l for q = q0 + quad*4 + r (C layout).
      ol = __builtin_amdgcn_mfma_f32_16x16x32_bf16(pa, ones, ol, 0, 0, 0);
      __builtin_amdgcn_s_setprio(0);
    }
  }

  // epilogue: ol[r] is already this lane's row-sum in C layout; no shuffles.
#pragma unroll
  for (int r = 0; r < 4; ++r) {
    const float invr = 1.0f / ol[r];
    unsigned short* ar =
        attnb + ((size_t)(b * SEQ + q0 + quad * 4 + r)) * DMODEL + h * DHEAD;
#pragma unroll
    for (int nt = 0; nt < 4; ++nt) ar[nt * 16 + lr] = f2bf(o[nt][r] * invr);
  }
}

// ---------------------------------------------------------------------------
// Launch
// ---------------------------------------------------------------------------
extern "C" void kernel_launch(void* const* d_in, const int* in_sizes, int n_in,
                              void* d_out, int out_size, void* d_ws, size_t ws_size,
                              hipStream_t stream) {
  const float* x    = (const float*)d_in[0];
  // d_in[1]: fixed causal tril mask -> handled analytically, never read.
  const float* Wqkv = (const float*)d_in[2];
  const float* Wo   = (const float*)d_in[3];
  const float* tau  = (const float*)d_in[4];
  float* out = (float*)d_out;

  // workspace layout (~50 MB)
  unsigned short* attnb = (unsigned short*)d_ws;                      // bf16 [B,S,D]
  unsigned short* Qh = attnb + (size_t)BATCH * SEQ * DMODEL;          // bf16 [B,H,S,DH]
  unsigned short* Kh = Qh + (size_t)BATCH * NHEAD * SEQ * DHEAD;
  unsigned short* Vh = Kh + (size_t)BATCH * NHEAD * SEQ * DHEAD;
  unsigned short* Xb = Vh + (size_t)BATCH * NHEAD * SEQ * DHEAD;      // bf16 [B*S][D]
  unsigned short* Wqkv_t = Xb + (size_t)BATCH * SEQ * DMODEL;         // bf16 [3D][D]
  unsigned short* Wo_t = Wqkv_t + (size_t)DMODEL * QKV_COLS;          // bf16 [D][D]
  unsigned short* Vt = Wo_t + (size_t)DMODEL * DMODEL;                // bf16 [BH][DH][S]

  const int M = BATCH * SEQ;  // 4096

  // 0) prep: bf16 conversion + fused weight transposes
  convert_x_kernel<<<(M * DMODEL) / (256 * 4), 256, 0, stream>>>(x, Xb);
  transpose_w2_kernel<<<dim3(128, 32), dim3(32, 8), 0, stream>>>(
      Wqkv, Wqkv_t, Wo, Wo_t);

  // 1) GEMM1 + fused qk-norm (2-phase 128^2 + XCD swizzle) -> Qh/Kh/Vh
  qkv_gemm_norm_kernel<<<dim3(QKV_COLS / 128, M / 128), 256, 0, stream>>>(
      Xb, Wqkv_t, tau, Qh, Kh, Vh);

  // 2) V -> V^T [BH][DH][S]
  vtrans_kernel<<<dim3(BATCH * NHEAD, SEQ / 64), 256, 0, stream>>>(Vh, Vt);

  // 3) causal MFMA flash attention -> attnb bf16 [B,S,D]
  attn_kernel<<<dim3(1024), 256, 0, stream>>>(Qh, Kh, Vt, attnb);

  // 4) out = attn @ Wo  (M=4096, N=1024, K=1024), f32 out
  //    64x128 tiles, 512 blocks = 2/CU, XCD-chunked swizzle
  sgemm_bf16_kernel<<<dim3(DMODEL / 128, M / 64), 256, 0, stream>>>(
      attnb, Wo_t, out, M, DMODEL, DMODEL);
}

// Round 6
// 193.160 us; speedup vs baseline: 1.0648x; 1.0063x over previous
//
#include <hip/hip_runtime.h>
#include <math.h>

// Problem constants (from reference): B=2, S=2048, D=1024, H=16, DH=64
#define BATCH 2
#define SEQ 2048
#define DMODEL 1024
#define NHEAD 16
#define DHEAD 64
#define QKV_COLS (3 * DMODEL)          // 3072
#define EPS 1e-8f
#define LOG2E 1.44269504f

typedef short bf16x8 __attribute__((ext_vector_type(8)));   // 8 bf16 (4 VGPRs)
typedef float f32x4 __attribute__((ext_vector_type(4)));    // 4 fp32 acc

// round-to-nearest-even float -> bf16 (as raw ushort)
static __device__ __forceinline__ unsigned short f2bf(float x) {
  unsigned u = __float_as_uint(x);
  u += 0x7fffu + ((u >> 16) & 1u);
  return (unsigned short)(u >> 16);
}

// pack two f32 -> one u32 of 2xbf16 in ONE VALU op (T12 recipe)
static __device__ __forceinline__ unsigned cvtpk(float lo, float hi) {
  unsigned r;
  asm("v_cvt_pk_bf16_f32 %0, %1, %2" : "=v"(r) : "v"(lo), "v"(hi));
  return r;
}

// async global->LDS, 16 B per lane (global_load_lds_dwordx4).
// LDS dest: wave-uniform base + lane*16 (m104/m108).
static __device__ __forceinline__ void async_ld16(const unsigned short* g,
                                                  unsigned short* l) {
  __builtin_amdgcn_global_load_lds(
      (const __attribute__((address_space(1))) void*)g,
      (__attribute__((address_space(3))) void*)(unsigned int)(unsigned long long)l,
      16, 0, 0);
}

// ---------------------------------------------------------------------------
// Prep (fused, R17): x f32->bf16 copy + both weight transposes, one launch.
// blocks 0..4095: convert; 4096..8191: transpose (block-uniform branch).
// ---------------------------------------------------------------------------
__global__ __launch_bounds__(256) void prep_kernel(
    const float* __restrict__ x, unsigned short* __restrict__ xb,
    const float* __restrict__ W0, unsigned short* __restrict__ Wt0,
    const float* __restrict__ W1, unsigned short* __restrict__ Wt1) {
  __shared__ float tile[32][33];
  const int bid = blockIdx.x;
  if (bid < 4096) {
    const size_t i = ((size_t)bid * 256 + threadIdx.x) * 4;
    const float4 a = *(const float4*)(x + i);
    ushort4 r;
    r.x = f2bf(a.x); r.y = f2bf(a.y); r.z = f2bf(a.z); r.w = f2bf(a.w);
    *(ushort4*)(xb + i) = r;
    return;
  }
  const int bxx = bid - 4096;
  const int bxi = bxx & 127;          // 0..127 (n-block)
  const int k0 = (bxx >> 7) * 32;     // 0..31 -> k offset
  const float* W;
  unsigned short* Wt;
  int N, n0;
  if (bxi < 96) { W = W0; Wt = Wt0; N = QKV_COLS; n0 = bxi * 32; }
  else          { W = W1; Wt = Wt1; N = DMODEL;   n0 = (bxi - 96) * 32; }
  const int K = DMODEL;
  const int tx = threadIdx.x & 31, ty = threadIdx.x >> 5;
#pragma unroll
  for (int i = 0; i < 4; ++i)
    tile[ty + i * 8][tx] = W[(size_t)(k0 + ty + i * 8) * N + n0 + tx];
  __syncthreads();
#pragma unroll
  for (int i = 0; i < 4; ++i)
    Wt[(size_t)(n0 + ty + i * 8) * K + k0 + tx] = f2bf(tile[tx][ty + i * 8]);
}

// ---------------------------------------------------------------------------
// GEMM2 — R17: 64x128 tiles, 512 blocks = 2/CU, XCD-chunked swizzle, and NEW
// chunk-XOR LDS swizzle (key (row>>1)&3): kills the 8-way ds_read_b128 bank
// conflict of 64B-row tiles. LDS[row][c] = global[row][c ^ ((row>>1)&3)];
// linear global_load_lds dest + pre-swizzled global source + swizzled read.
// ---------------------------------------------------------------------------
__global__ __launch_bounds__(256) void sgemm_bf16_kernel(
    const unsigned short* __restrict__ A, const unsigned short* __restrict__ Bt,
    float* __restrict__ C, int M, int N, int K) {
  __shared__ unsigned short As[2][64 * 32];    // [buf][m][k]   4 KiB each
  __shared__ unsigned short Bs[2][128 * 32];   // [buf][n][k]   8 KiB each

  const int t = threadIdx.x;
  const int w = t >> 6;
  const int lane = t & 63;
  const int quad = lane >> 4;
  const int lr = lane & 15;
  const int rk = (lr >> 1) & 3;      // read-side XOR key = (row>>1)&3

  // T1 swizzle: dispatch-linear id -> XCD-chunked logical id (512 %% 8 == 0)
  const int orig = blockIdx.y * gridDim.x + blockIdx.x;   // gridDim.x == 8
  const int wg = (orig & 7) * 64 + (orig >> 3);
  const int bx = wg & 7, by = wg >> 3;                    // by: 0..63
  const int m0 = by * 64;
  const int n0 = bx * 128;

  const int srow = lane >> 2;                              // 0..15
  const int scol = ((lane & 3) ^ ((lane >> 3) & 3)) * 8;   // pre-swizzled chunk

  // 12 async_ld16 per K-step: 4 A-quarters (16 rows) + 8 B-eighths.
  auto stage = [&](int k0, int bb) {
#pragma unroll
    for (int ii = 0; ii < 3; ++ii) {
      const int fi = w * 3 + ii;
      if (fi < 4) {
        async_ld16(A + (size_t)(m0 + fi * 16 + srow) * K + k0 + scol,
                   &As[bb][fi * 512]);
      } else {
        const int g = fi - 4;
        async_ld16(Bt + (size_t)(n0 + g * 16 + srow) * K + k0 + scol,
                   &Bs[bb][g * 512]);
      }
    }
  };

  f32x4 acc[4][2];
  const f32x4 zero4 = {0.f, 0.f, 0.f, 0.f};
#pragma unroll
  for (int i = 0; i < 4; ++i)
#pragma unroll
    for (int j = 0; j < 2; ++j) acc[i][j] = zero4;

  stage(0, 0);
  int bb = 0;
  for (int k0 = 0; k0 < K; k0 += 32, bb ^= 1) {
    __syncthreads();
    if (k0 + 32 < K) stage(k0 + 32, bb ^ 1);

    bf16x8 af[4], bfr[2];
#pragma unroll
    for (int i = 0; i < 4; ++i)
      af[i] = *(const bf16x8*)&As[bb][(i * 16 + lr) * 32 + ((quad ^ rk) * 8)];
#pragma unroll
    for (int j = 0; j < 2; ++j)
      bfr[j] = *(const bf16x8*)&Bs[bb][(w * 32 + j * 16 + lr) * 32 + ((quad ^ rk) * 8)];
#pragma unroll
    for (int i = 0; i < 4; ++i)
#pragma unroll
      for (int j = 0; j < 2; ++j)
        acc[i][j] = __builtin_amdgcn_mfma_f32_16x16x32_bf16(af[i], bfr[j], acc[i][j], 0, 0, 0);
  }

#pragma unroll
  for (int i = 0; i < 4; ++i)
#pragma unroll
    for (int r = 0; r < 4; ++r) {
      float* c = C + (size_t)(m0 + i * 16 + quad * 4 + r) * N + n0 + w * 32 + lr;
#pragma unroll
      for (int j = 0; j < 2; ++j) c[j * 16] = acc[i][j][r];
    }
}

// ---------------------------------------------------------------------------
// GEMM1 + fused qk-norm — R17: 128x128 2-phase + T1 XCD swizzle + NEW
// chunk-XOR LDS swizzle (same derivation as sgemm; kills the 3.1M 8-way
// bank conflicts R16's counters showed). Staging bases are multiples of 16
// rows so the swizzle key reduces to lane bits only.
// ---------------------------------------------------------------------------
__global__ __launch_bounds__(256) void qkv_gemm_norm_kernel(
    const unsigned short* __restrict__ A, const unsigned short* __restrict__ Bt,
    const float* __restrict__ tau,
    unsigned short* __restrict__ Qh, unsigned short* __restrict__ Kh,
    unsigned short* __restrict__ Vh) {
  __shared__ unsigned short As[2][128 * 32];
  __shared__ unsigned short Bs[2][128 * 32];

  const int K = DMODEL;
  const int t = threadIdx.x;
  const int w = t >> 6;
  const int lane = t & 63;
  const int quad = lane >> 4;
  const int lr = lane & 15;
  const int wr = w >> 1, wc = w & 1;
  const int rk = (lr >> 1) & 3;      // read-side XOR key

  // T1 swizzle: 768 blocks (24 x 32) -> XCD k gets 96 contiguous ids.
  const int orig = blockIdx.y * gridDim.x + blockIdx.x;   // gridDim.x == 24
  const int wg = (orig & 7) * 96 + (orig >> 3);
  const int bx = wg % 24, by = wg / 24;
  const int m0 = by * 128;
  const int n0 = bx * 128;

  const int srow = w * 32 + (lane >> 2);
  const int scol = ((lane & 3) ^ ((lane >> 3) & 3)) * 8;   // pre-swizzled chunk
  const unsigned short* ga = A + (size_t)(m0 + srow) * K + scol;
  const unsigned short* gb = Bt + (size_t)(n0 + srow) * K + scol;

  auto stage = [&](int k0, int bb) {
#pragma unroll
    for (int i = 0; i < 2; ++i) {
      async_ld16(ga + (size_t)(i * 16) * K + k0, &As[bb][(w * 32 + i * 16) * 32]);
      async_ld16(gb + (size_t)(i * 16) * K + k0, &Bs[bb][(w * 32 + i * 16) * 32]);
    }
  };

  f32x4 acc[4][4];
  const f32x4 zero4 = {0.f, 0.f, 0.f, 0.f};
#pragma unroll
  for (int i = 0; i < 4; ++i)
#pragma unroll
    for (int j = 0; j < 4; ++j) acc[i][j] = zero4;

  stage(0, 0);
  int bb = 0;
  for (int k0 = 0; k0 < K; k0 += 32, bb ^= 1) {
    __syncthreads();
    if (k0 + 32 < K) stage(k0 + 32, bb ^ 1);

    bf16x8 af[4], bfr[4];
#pragma unroll
    for (int i = 0; i < 4; ++i)
      af[i] = *(const bf16x8*)&As[bb][(wr * 64 + i * 16 + lr) * 32 + ((quad ^ rk) * 8)];
#pragma unroll
    for (int j = 0; j < 4; ++j)
      bfr[j] = *(const bf16x8*)&Bs[bb][(wc * 64 + j * 16 + lr) * 32 + ((quad ^ rk) * 8)];
#pragma unroll
    for (int i = 0; i < 4; ++i)
#pragma unroll
      for (int j = 0; j < 4; ++j)
        acc[i][j] = __builtin_amdgcn_mfma_f32_16x16x32_bf16(af[i], bfr[j], acc[i][j], 0, 0, 0);
  }

  // Epilogue: wave-uniform (which, head) from column block.
  const int col0 = n0 + wc * 64;
  const int which = col0 >> 10;             // 0=q, 1=k, 2=v
  const int h = (col0 & 1023) >> 6;
  const float tsc = tau[h] * 0.125f * LOG2E;
  unsigned short* dst = (which == 0) ? Qh : (which == 1) ? Kh : Vh;

#pragma unroll
  for (int i = 0; i < 4; ++i)
#pragma unroll
    for (int r = 0; r < 4; ++r) {
      const int s = m0 + wr * 64 + i * 16 + quad * 4 + r;   // global row 0..4095
      unsigned short* ar =
          dst + (((size_t)((s >> 11) * NHEAD + h)) * SEQ + (s & 2047)) * DHEAD;
      float scale;
      if (which == 2) {
        scale = 1.0f;
      } else {
        float ss = 0.f;
#pragma unroll
        for (int j = 0; j < 4; ++j) ss += acc[i][j][r] * acc[i][j][r];
        ss += __shfl_xor(ss, 1, 16);
        ss += __shfl_xor(ss, 2, 16);
        ss += __shfl_xor(ss, 4, 16);
        ss += __shfl_xor(ss, 8, 16);
        scale = 1.0f / (sqrtf(ss) + EPS);
        if (which == 0) scale *= tsc;       // tau/sqrt(DH) * log2e into Q
      }
#pragma unroll
      for (int j = 0; j < 4; ++j) ar[j * 16 + lr] = f2bf(acc[i][j][r] * scale);
    }
}

// ---------------------------------------------------------------------------
// V transpose: Vh [BH][S][DH] -> Vt [BH][DH][S]. 64x64 LDS tiles.
// ---------------------------------------------------------------------------
__global__ __launch_bounds__(256) void vtrans_kernel(
    const unsigned short* __restrict__ Vh, unsigned short* __restrict__ Vt) {
  __shared__ unsigned short tile[64][72];
  const int bh = blockIdx.x;
  const int s0 = blockIdx.y * 64;
  const int t = threadIdx.x;
  const int sr = t >> 2;          // 0..63
  const int dc = (t & 3) * 16;    // 0,16,32,48
  const unsigned short* src = Vh + ((size_t)bh * SEQ + s0 + sr) * DHEAD + dc;
  *(bf16x8*)&tile[sr][dc]     = *(const bf16x8*)(src);
  *(bf16x8*)&tile[sr][dc + 8] = *(const bf16x8*)(src + 8);
  __syncthreads();
  const int dr = t >> 2;          // 0..63 (d row)
  const int sc = (t & 3) * 16;    // s chunk
  unsigned short buf[16];
#pragma unroll
  for (int i = 0; i < 16; ++i) buf[i] = tile[sc + i][dr];
  unsigned short* dst = Vt + ((size_t)bh * DHEAD + dr) * SEQ + s0 + sc;
  *(bf16x8*)dst       = *(const bf16x8*)buf;
  *(bf16x8*)(dst + 8) = *(const bf16x8*)(buf + 8);
}

// ---------------------------------------------------------------------------
// Causal flash attention — R16 (unchanged; it worked).
// grid 1024, 4 blocks/CU, XOR-swizzled K/V, P in registers via permlane
// swaps, cvt_pk packing, row-sum via MFMA-with-ones, setprio.
// ---------------------------------------------------------------------------
__global__ __launch_bounds__(256, 4) void attn_kernel(
    const unsigned short* __restrict__ Qh, const unsigned short* __restrict__ Kh,
    const unsigned short* __restrict__ Vt, unsigned short* __restrict__ attnb) {
  __shared__ unsigned short Ks[2][64 * 64];   // [buf][key][d']  swizzled chunks
  __shared__ unsigned short Vs[2][64 * 64];   // [buf][d][key']  swizzled chunks

  const int idx = blockIdx.x;
  const int bh = idx & 31;
  const int i2 = idx >> 5;                 // 0..31
  const int seg = i2 >> 3, G = i2 & 7;
  const int qb = (seg == 0) ? 31 - G : (seg == 1) ? G : (seg == 2) ? 23 - G : 8 + G;
  const int b = bh >> 4;
  const int h = bh & 15;
  const int t = threadIdx.x;
  const int w = t >> 6;
  const int lane = t & 63;
  const int quad = lane >> 4;
  const int lr = lane & 15;
  const int sw = lr & 7;                   // read-side XOR swizzle key (row&7)

  const unsigned short* Qp = Qh + (size_t)bh * SEQ * DHEAD;
  const unsigned short* Kp = Kh + (size_t)bh * SEQ * DHEAD;
  const unsigned short* Vp = Vt + (size_t)bh * DHEAD * SEQ;

  const int rrow = lane >> 3;                        // 0..7
  const int swc = ((lane & 7) ^ rrow) * 8;           // swizzled chunk, in shorts
  const int f0 = w * 4;

  auto stage = [&](int k0, int bb) {
#pragma unroll
    for (int ii = 0; ii < 4; ++ii) {
      const int fi = f0 + ii;
      if (fi < 8) {   // K tile rows = keys
        async_ld16(Kp + (size_t)(k0 + fi * 8 + rrow) * DHEAD + swc,
                   &Ks[bb][fi * 512]);
      } else {        // V^T tile rows = d
        const int g = fi - 8;
        async_ld16(Vp + (size_t)(g * 8 + rrow) * SEQ + k0 + swc,
                   &Vs[bb][g * 512]);
      }
    }
  };

  const f32x4 zero4 = {0.f, 0.f, 0.f, 0.f};
  f32x4 o[4];
  o[0] = o[1] = o[2] = o[3] = zero4;
  f32x4 ol = zero4;                 // row-sum accumulator (MFMA-with-ones)

  bf16x8 ones;
#pragma unroll
  for (int i = 0; i < 8; ++i) ones[i] = (short)0x3F80;   // bf16 1.0

  const int q0 = qb * 64 + w * 16;
  const unsigned short* qr = Qp + (size_t)(q0 + lr) * DHEAD;
  const bf16x8 aq0 = *(const bf16x8*)(qr + quad * 8);
  const bf16x8 aq1 = *(const bf16x8*)(qr + 32 + quad * 8);
  const int qrow = q0 + lr;        // this lane's q row (for diagonal mask)

  const int kend = qb * 64;        // last step's k0 (diagonal step)

  stage(0, 0);
  int bb = 0;

  for (int k0 = 0; k0 <= kend; k0 += 64, bb ^= 1) {
    __syncthreads();                       // buf bb staged; prev reads done
    if (k0 < kend) stage(k0 + 64, bb ^ 1);

    // --- QK^T (swapped: S^T = K * Q^T; lane holds 16 keys for q=lr) ---
    f32x4 c[4];
    __builtin_amdgcn_s_setprio(1);
#pragma unroll
    for (int kt = 0; kt < 4; ++kt) {
      const bf16x8 kf0 =
          *(const bf16x8*)&Ks[bb][(kt * 16 + lr) * 64 + ((quad ^ sw) * 8)];
      const bf16x8 kf1 =
          *(const bf16x8*)&Ks[bb][(kt * 16 + lr) * 64 + (((4 | quad) ^ sw) * 8)];
      f32x4 tt = __builtin_amdgcn_mfma_f32_16x16x32_bf16(kf0, aq0, zero4, 0, 0, 0);
      c[kt] = __builtin_amdgcn_mfma_f32_16x16x32_bf16(kf1, aq1, tt, 0, 0, 0);
    }
    __builtin_amdgcn_s_setprio(0);

    // --- fixed-max exp2 softmax, packed to bf16 via v_cvt_pk (1 VALU/pair)
    unsigned plo[4], phi[4];
    if (k0 == kend) {                      // diagonal step: causal mask
#pragma unroll
      for (int kt = 0; kt < 4; ++kt) {
        float p[4];
#pragma unroll
        for (int r = 0; r < 4; ++r) {
          const int key = k0 + kt * 16 + quad * 4 + r;
          p[r] = (key <= qrow) ? exp2f(c[kt][r]) : 0.f;
        }
        plo[kt] = cvtpk(p[0], p[1]);
        phi[kt] = cvtpk(p[2], p[3]);
      }
    } else {
#pragma unroll
      for (int kt = 0; kt < 4; ++kt) {
        plo[kt] = cvtpk(exp2f(c[kt][0]), exp2f(c[kt][1]));
        phi[kt] = cvtpk(exp2f(c[kt][2]), exp2f(c[kt][3]));
      }
    }

    // --- permlane butterfly: compute layout -> PV A-operand layout ---
#pragma unroll
    for (int c2 = 0; c2 < 2; ++c2) {
      unsigned aLo = plo[2 * c2],     aHi = phi[2 * c2];
      unsigned bLo = plo[2 * c2 + 1], bHi = phi[2 * c2 + 1];
      asm("v_permlane32_swap_b32 %0, %1" : "+v"(aLo), "+v"(bLo));
      asm("v_permlane32_swap_b32 %0, %1" : "+v"(aHi), "+v"(bHi));
      asm("v_permlane16_swap_b32 %0, %1" : "+v"(aLo), "+v"(bLo));
      asm("v_permlane16_swap_b32 %0, %1" : "+v"(aHi), "+v"(bHi));
      union { unsigned u[4]; bf16x8 v; } pk;
      pk.u[0] = aLo; pk.u[1] = aHi; pk.u[2] = bLo; pk.u[3] = bHi;
      const bf16x8 pa = pk.v;
      __builtin_amdgcn_s_setprio(1);
#pragma unroll
      for (int nt = 0; nt < 4; ++nt) {
        const bf16x8 vb = *(const bf16x8*)&Vs[bb][(nt * 16 + lr) * 64 +
                                                  (((c2 * 4 + quad) ^ sw) * 8)];
        o[nt] = __builtin_amdgcn_mfma_f32_16x16x32_bf16(pa, vb, o[nt], 0, 0, 0);
      }
      // row-sum: all 16 output cols identical = sum_k P[q][k]; accumulates
      // across steps. ol[r] = l for q = q0 + quad*4 + r (C layout).
      ol = __builtin_amdgcn_mfma_f32_16x16x32_bf16(pa, ones, ol, 0, 0, 0);
      __builtin_amdgcn_s_setprio(0);
    }
  }

  // epilogue: ol[r] is already this lane's row-sum in C layout; no shuffles.
#pragma unroll
  for (int r = 0; r < 4; ++r) {
    const float invr = 1.0f / ol[r];
    unsigned short* ar =
        attnb + ((size_t)(b * SEQ + q0 + quad * 4 + r)) * DMODEL + h * DHEAD;
#pragma unroll
    for (int nt = 0; nt < 4; ++nt) ar[nt * 16 + lr] = f2bf(o[nt][r] * invr);
  }
}

// ---------------------------------------------------------------------------
// Launch
// ---------------------------------------------------------------------------
extern "C" void kernel_launch(void* const* d_in, const int* in_sizes, int n_in,
                              void* d_out, int out_size, void* d_ws, size_t ws_size,
                              hipStream_t stream) {
  const float* x    = (const float*)d_in[0];
  // d_in[1]: fixed causal tril mask -> handled analytically, never read.
  const float* Wqkv = (const float*)d_in[2];
  const float* Wo   = (const float*)d_in[3];
  const float* tau  = (const float*)d_in[4];
  float* out = (float*)d_out;

  // workspace layout (~50 MB)
  unsigned short* attnb = (unsigned short*)d_ws;                      // bf16 [B,S,D]
  unsigned short* Qh = attnb + (size_t)BATCH * SEQ * DMODEL;          // bf16 [B,H,S,DH]
  unsigned short* Kh = Qh + (size_t)BATCH * NHEAD * SEQ * DHEAD;
  unsigned short* Vh = Kh + (size_t)BATCH * NHEAD * SEQ * DHEAD;
  unsigned short* Xb = Vh + (size_t)BATCH * NHEAD * SEQ * DHEAD;      // bf16 [B*S][D]
  unsigned short* Wqkv_t = Xb + (size_t)BATCH * SEQ * DMODEL;         // bf16 [3D][D]
  unsigned short* Wo_t = Wqkv_t + (size_t)DMODEL * QKV_COLS;          // bf16 [D][D]
  unsigned short* Vt = Wo_t + (size_t)DMODEL * DMODEL;                // bf16 [BH][DH][S]

  const int M = BATCH * SEQ;  // 4096

  // 0) prep: fused bf16 conversion + both weight transposes (one launch)
  prep_kernel<<<dim3(8192), 256, 0, stream>>>(x, Xb, Wqkv, Wqkv_t, Wo, Wo_t);

  // 1) GEMM1 + fused qk-norm (2-phase 128^2 + XCD + LDS swizzle) -> Qh/Kh/Vh
  qkv_gemm_norm_kernel<<<dim3(QKV_COLS / 128, M / 128), 256, 0, stream>>>(
      Xb, Wqkv_t, tau, Qh, Kh, Vh);

  // 2) V -> V^T [BH][DH][S]
  vtrans_kernel<<<dim3(BATCH * NHEAD, SEQ / 64), 256, 0, stream>>>(Vh, Vt);

  // 3) causal MFMA flash attention -> attnb bf16 [B,S,D]
  attn_kernel<<<dim3(1024), 256, 0, stream>>>(Qh, Kh, Vt, attnb);

  // 4) out = attn @ Wo  (M=4096, N=1024, K=1024), f32 out
  //    64x128 tiles, 512 blocks = 2/CU, XCD + LDS swizzle
  sgemm_bf16_kernel<<<dim3(DMODEL / 128, M / 64), 256, 0, stream>>>(
      attnb, Wo_t, out, M, DMODEL, DMODEL);
}